// Round 1
// baseline (1052.707 us; speedup 1.0000x reference)
//
#include <hip/hip_runtime.h>
#include <math.h>

constexpr int F  = 128;   // n_filters == n_atom_basis
constexpr int KN = 48;    // neighbors per atom
constexpr int NG = 25;    // gaussians

__device__ __forceinline__ float ssp(float x) {
    // shifted softplus: log(0.5*exp(x)+0.5) = softplus(x) - ln2 (stable form)
    return fmaxf(x, 0.0f) + log1pf(__expf(-fabsf(x))) - 0.69314718055994531f;
}

// y = embed[Z] @ in2f_w   (one atom per block, 128 threads)
__global__ __launch_bounds__(128) void k_proj_y(
    const float* __restrict__ embed, const int* __restrict__ Z,
    const float* __restrict__ in2f_w, float* __restrict__ y, int N)
{
    int n = blockIdx.x;
    int f = threadIdx.x;
    __shared__ float sx[F];
    sx[f] = embed[Z[n] * F + f];
    __syncthreads();
    float acc = 0.f;
    #pragma unroll 8
    for (int c = 0; c < F; ++c)
        acc = fmaf(sx[c], in2f_w[c * F + f], acc);
    y[n * F + f] = acc;
}

// One atom per block (256 threads = 2 groups of 128).
// Phases: cut/mask -> gaussians -> H' = ssp(g@f1w+b)*cut -> W=H'@f2w (+cut*f2b)
//         -> gather y, aggregate over k -> output net + residual.
__global__ __launch_bounds__(256) void k_main(
    const float* __restrict__ dR, const int* __restrict__ nbr,
    const float* __restrict__ y,
    const float* __restrict__ f1_w, const float* __restrict__ f1_b,
    const float* __restrict__ f2_w, const float* __restrict__ f2_b,
    const float* __restrict__ o1_w, const float* __restrict__ o1_b,
    const float* __restrict__ o2_w, const float* __restrict__ o2_b,
    const float* __restrict__ embed, const int* __restrict__ Z,
    float* __restrict__ out, int N)
{
    int n   = blockIdx.x;
    int tid = threadIdx.x;
    int p   = tid >> 7;      // 0 or 1
    int f   = tid & 127;

    __shared__ float sdR[KN];
    __shared__ float scut[KN];
    __shared__ int   sidx[KN];
    __shared__ float G[KN][32];     // 25 used, padded rows
    __shared__ float H[KN][F];      // cut-scaled ssp(filter1) output
    __shared__ float part[2][F];
    __shared__ float sagg[F];
    __shared__ float su[F];

    // phase 1: distances, cutoff, padding mask
    if (tid < KN) {
        float d = dR[n * KN + tid];
        int   i = nbr[n * KN + tid];
        sdR[tid] = d;
        float cut = 0.5f * (cosf(d * 0.62831853071795864769f) + 1.0f); // pi/5
        cut *= (d < 5.0f) ? 1.0f : 0.0f;
        cut *= (i < N)    ? 1.0f : 0.0f;
        scut[tid] = cut;
        sidx[tid] = (i < N) ? i : 0;
    }
    __syncthreads();

    // phase 2: gaussian smearing G[k][j]
    constexpr float width = 5.0f / 24.0f;
    constexpr float coeff = -0.5f / (width * width);
    for (int e = tid; e < KN * NG; e += 256) {
        int k = e / NG, j = e - k * NG;
        float d = sdR[k] - (float)j * width;
        G[k][j] = __expf(coeff * d * d);
    }
    __syncthreads();

    // phase 3: H'[k][f] = ssp(g@f1w + f1b) * cut[k]
    {
        float f1bf = f1_b[f];
        for (int k = p; k < KN; k += 2) {
            float h = f1bf;
            #pragma unroll
            for (int j = 0; j < NG; ++j)
                h = fmaf(G[k][j], f1_w[j * F + f], h);
            H[k][f] = ssp(h) * scut[k];
        }
    }
    __syncthreads();

    // phase 4: W[k][f] = (H'@f2w)[k][f] + cut[k]*f2b[f]; agg[f] = sum_k y[idx_k][f]*W[k][f]
    float acc[KN / 2];
    #pragma unroll
    for (int kk = 0; kk < KN / 2; ++kk) acc[kk] = 0.f;

    for (int c = 0; c < F; c += 4) {
        float w0 = f2_w[(c + 0) * F + f];
        float w1 = f2_w[(c + 1) * F + f];
        float w2 = f2_w[(c + 2) * F + f];
        float w3 = f2_w[(c + 3) * F + f];
        #pragma unroll
        for (int kk = 0; kk < KN / 2; ++kk) {
            int k = 2 * kk + p;
            const float4 h4 = *reinterpret_cast<const float4*>(&H[k][c]);
            acc[kk] = fmaf(h4.x, w0, fmaf(h4.y, w1, fmaf(h4.z, w2, fmaf(h4.w, w3, acc[kk]))));
        }
    }
    {
        float f2bf = f2_b[f];
        float aggp = 0.f;
        #pragma unroll
        for (int kk = 0; kk < KN / 2; ++kk) {
            int k = 2 * kk + p;
            float yv = y[sidx[k] * F + f];
            aggp = fmaf(yv, acc[kk] + scut[k] * f2bf, aggp);
        }
        part[p][f] = aggp;
    }
    __syncthreads();

    // phase 5: output network + residual (first 128 threads)
    if (tid < F) sagg[f] = part[0][f] + part[1][f];
    __syncthreads();
    if (tid < F) {
        float t = o1_b[f];
        #pragma unroll 8
        for (int c = 0; c < F; ++c)
            t = fmaf(sagg[c], o1_w[c * F + f], t);
        su[f] = ssp(t);
    }
    __syncthreads();
    if (tid < F) {
        float v = o2_b[f];
        #pragma unroll 8
        for (int c = 0; c < F; ++c)
            v = fmaf(su[c], o2_w[c * F + f], v);
        out[n * F + f] = embed[Z[n] * F + f] + v;
    }
}

extern "C" void kernel_launch(void* const* d_in, const int* in_sizes, int n_in,
                              void* d_out, int out_size, void* d_ws, size_t ws_size,
                              hipStream_t stream) {
    const float* dR    = (const float*)d_in[0];
    const int*   Z     = (const int*)  d_in[1];
    const int*   nbr   = (const int*)  d_in[2];
    const float* embed = (const float*)d_in[3];
    const float* in2f  = (const float*)d_in[4];
    const float* f1w   = (const float*)d_in[5];
    const float* f1b   = (const float*)d_in[6];
    const float* f2w   = (const float*)d_in[7];
    const float* f2b   = (const float*)d_in[8];
    const float* o1w   = (const float*)d_in[9];
    const float* o1b   = (const float*)d_in[10];
    const float* o2w   = (const float*)d_in[11];
    const float* o2b   = (const float*)d_in[12];

    int N = in_sizes[1];          // Z has N elements
    float* y = (float*)d_ws;      // N*128 floats

    k_proj_y<<<N, 128, 0, stream>>>(embed, Z, in2f, y, N);
    k_main<<<N, 256, 0, stream>>>(dR, nbr, y, f1w, f1b, f2w, f2b,
                                  o1w, o1b, o2w, o2b, embed, Z,
                                  (float*)d_out, N);
}

// Round 2
// 224.048 us; speedup vs baseline: 4.6986x; 4.6986x over previous
//
#include <hip/hip_runtime.h>
#include <math.h>

constexpr int F  = 128;
constexpr int KN = 48;
constexpr int NG = 25;

typedef short bf16x8 __attribute__((ext_vector_type(8)));
typedef float f32x4  __attribute__((ext_vector_type(4)));

__device__ __forceinline__ float ssp(float x) {
    // softplus(x) - ln2 = max(x,0) + log(0.5*exp(-|x|) + 0.5)   (no overflow)
    return fmaxf(x, 0.0f) + __logf(fmaf(0.5f, __expf(-fabsf(x)), 0.5f));
}

__device__ __forceinline__ unsigned short f2bf(float x) {
    unsigned int u = __float_as_uint(x);
    unsigned int r = (u + 0x7FFFu + ((u >> 16) & 1u)) >> 16;   // RNE
    return (unsigned short)r;
}

// Pre-swizzle f1_w / f2_w into B-fragment-major bf16 buffers.
// frag layout for 16x16x32 bf16 B: lane l holds B[k=(l>>4)*8+j][col=(l&15)] j=0..7
// f1frag[(nt*64+l)*8+j], nt=0..7, k-tile 0 (rows >=25 zero)
// f2frag[((kt*8+nt)*64+l)*8+j], kt=0..3
__global__ __launch_bounds__(256) void k_prep(
    const float* __restrict__ f1w, const float* __restrict__ f2w,
    unsigned short* __restrict__ f1frag, unsigned short* __restrict__ f2frag)
{
    int t = blockIdx.x * 256 + threadIdx.x;
    if (t < 4096) {                       // f1: 8*64*8
        int j = t & 7, l = (t >> 3) & 63, nt = t >> 9;
        int k = ((l >> 4) << 3) + j;
        int col = nt * 16 + (l & 15);
        f1frag[t] = (k < NG) ? f2bf(f1w[k * F + col]) : (unsigned short)0;
    } else if (t < 4096 + 16384) {        // f2: 4*8*64*8
        int e = t - 4096;
        int j = e & 7, l = (e >> 3) & 63, nt = (e >> 9) & 7, kt = e >> 12;
        int k = kt * 32 + ((l >> 4) << 3) + j;
        int col = nt * 16 + (l & 15);
        f2frag[e] = f2bf(f2w[k * F + col]);
    }
}

// y = embed[Z] @ in2f_w (fp32)
__global__ __launch_bounds__(128) void k_proj_y(
    const float* __restrict__ embed, const int* __restrict__ Z,
    const float* __restrict__ in2f_w, float* __restrict__ y, int N)
{
    int n = blockIdx.x;
    int f = threadIdx.x;
    __shared__ float sx[F];
    sx[f] = embed[Z[n] * F + f];
    __syncthreads();
    float acc = 0.f;
    #pragma unroll 8
    for (int c = 0; c < F; ++c)
        acc = fmaf(sx[c], in2f_w[c * F + f], acc);
    y[n * F + f] = acc;
}

// One atom per block, 4 waves. Wave w owns col-tiles nt={2w,2w+1}, all 3 row-tiles.
// MFMA1: G[48x32]@f1w[32x128] -> ssp*cut -> H' bf16 in LDS (XOR-swizzled)
// MFMA2: H'[48x128]@f2w[128x128] -> +cut*f2b -> gather y -> agg (written to d_out)
__global__ __launch_bounds__(256) void k_pair(
    const float* __restrict__ dR, const int* __restrict__ nbr,
    const float* __restrict__ y,
    const unsigned short* __restrict__ f1frag, const unsigned short* __restrict__ f2frag,
    const float* __restrict__ f1_b, const float* __restrict__ f2_b,
    float* __restrict__ agg_out, int N)
{
    int n   = blockIdx.x;
    int tid = threadIdx.x;
    int w   = tid >> 6;
    int l   = tid & 63;
    int lr  = l & 15;
    int lg  = l >> 4;

    __shared__ float sdR[KN];
    __shared__ float scut[KN];
    __shared__ int   sidx[KN];
    __shared__ unsigned short Hs[KN * F];   // bf16, swizzled: idx = r*128 + (col ^ ((r&15)<<3))

    if (tid < KN) {
        float d = dR[n * KN + tid];
        int   i = nbr[n * KN + tid];
        sdR[tid] = d;
        float cut = 0.5f * (cosf(d * 0.62831853071795864769f) + 1.0f);
        cut = (d < 5.0f && i < N) ? cut : 0.0f;   // cutoff * padding mask
        scut[tid] = cut;
        sidx[tid] = (i < N) ? i : 0;
    }
    __syncthreads();

    // ---- A-frags for MFMA1 computed in registers (gaussian smearing) ----
    constexpr float width = 5.0f / 24.0f;
    constexpr float coeff = -0.5f / (width * width);
    bf16x8 a1[3];
    #pragma unroll
    for (int mt = 0; mt < 3; ++mt) {
        float d = sdR[mt * 16 + lr];
        #pragma unroll
        for (int j = 0; j < 8; ++j) {
            int k = lg * 8 + j;
            float g = 0.f;
            if (k < NG) { float t = d - (float)k * width; g = __expf(coeff * t * t); }
            a1[mt][j] = (short)f2bf(g);
        }
    }

    // ---- MFMA1 ----
    f32x4 zero = {0.f, 0.f, 0.f, 0.f};
    f32x4 c1[3][2];
    #pragma unroll
    for (int ntl = 0; ntl < 2; ++ntl) {
        int nt = 2 * w + ntl;
        bf16x8 b = *reinterpret_cast<const bf16x8*>(f1frag + ((nt * 64 + l) << 3));
        #pragma unroll
        for (int mt = 0; mt < 3; ++mt)
            c1[mt][ntl] = __builtin_amdgcn_mfma_f32_16x16x32_bf16(a1[mt], b, zero, 0, 0, 0);
    }

    // ---- epilogue1: H' = ssp(c1 + f1_b) * cut  -> LDS bf16 (swizzled) ----
    #pragma unroll
    for (int ntl = 0; ntl < 2; ++ntl) {
        int fcol = (2 * w + ntl) * 16 + lr;
        float fb = f1_b[fcol];
        #pragma unroll
        for (int mt = 0; mt < 3; ++mt) {
            #pragma unroll
            for (int jr = 0; jr < 4; ++jr) {
                int r = mt * 16 + lg * 4 + jr;
                float hs = ssp(c1[mt][ntl][jr] + fb) * scut[r];
                Hs[r * F + (fcol ^ ((r & 15) << 3))] = f2bf(hs);
            }
        }
    }
    __syncthreads();

    // ---- MFMA2: W = H' @ f2w ----
    f32x4 acc[3][2];
    #pragma unroll
    for (int mt = 0; mt < 3; ++mt) { acc[mt][0] = zero; acc[mt][1] = zero; }
    #pragma unroll
    for (int kt = 0; kt < 4; ++kt) {
        bf16x8 b0 = *reinterpret_cast<const bf16x8*>(f2frag + (((kt * 8 + 2 * w + 0) * 64 + l) << 3));
        bf16x8 b1 = *reinterpret_cast<const bf16x8*>(f2frag + (((kt * 8 + 2 * w + 1) * 64 + l) << 3));
        #pragma unroll
        for (int mt = 0; mt < 3; ++mt) {
            int r = mt * 16 + lr;
            int idx = r * F + ((kt * 32 + lg * 8) ^ ((r & 15) << 3));
            bf16x8 a2 = *reinterpret_cast<const bf16x8*>(&Hs[idx]);
            acc[mt][0] = __builtin_amdgcn_mfma_f32_16x16x32_bf16(a2, b0, acc[mt][0], 0, 0, 0);
            acc[mt][1] = __builtin_amdgcn_mfma_f32_16x16x32_bf16(a2, b1, acc[mt][1], 0, 0, 0);
        }
    }

    // ---- epilogue2: + cut*f2_b, gather y (fp32), aggregate over 48 neighbors ----
    int fcolv[2]; float f2bv[2]; float aggv[2] = {0.f, 0.f};
    #pragma unroll
    for (int ntl = 0; ntl < 2; ++ntl) {
        fcolv[ntl] = (2 * w + ntl) * 16 + lr;
        f2bv[ntl]  = f2_b[fcolv[ntl]];
    }
    #pragma unroll
    for (int mt = 0; mt < 3; ++mt) {
        #pragma unroll
        for (int jr = 0; jr < 4; ++jr) {
            int r = mt * 16 + lg * 4 + jr;
            float cutv = scut[r];
            int   base = sidx[r] * F;
            #pragma unroll
            for (int ntl = 0; ntl < 2; ++ntl) {
                float wv = acc[mt][ntl][jr] + cutv * f2bv[ntl];
                aggv[ntl] = fmaf(wv, y[base + fcolv[ntl]], aggv[ntl]);
            }
        }
    }
    #pragma unroll
    for (int ntl = 0; ntl < 2; ++ntl) {
        float v = aggv[ntl];
        v += __shfl_xor(v, 16);
        v += __shfl_xor(v, 32);
        if (lg == 0) agg_out[n * F + fcolv[ntl]] = v;
    }
}

// Output network (fp32, batched 32 atoms/block for weight reuse).
// agg lives in `out`; overwritten in place with x + v.
__global__ __launch_bounds__(256) void k_out(
    const float* __restrict__ o1w, const float* __restrict__ o1b,
    const float* __restrict__ o2w, const float* __restrict__ o2b,
    const float* __restrict__ embed, const int* __restrict__ Z,
    float* __restrict__ out, int N)
{
    int a0  = blockIdx.x * 32;
    int tid = threadIdx.x;
    int p   = tid >> 7;          // atom half: p*16 .. p*16+15
    int f   = tid & 127;
    __shared__ float sagg[32][F];
    __shared__ float ssu[32][F];

    for (int a = p; a < 32; a += 2) {
        int n = a0 + a;
        sagg[a][f] = (n < N) ? out[n * F + f] : 0.f;
    }
    __syncthreads();

    float acc[16];
    #pragma unroll
    for (int i = 0; i < 16; ++i) acc[i] = 0.f;
    for (int c = 0; c < F; c += 4) {
        float w0 = o1w[(c + 0) * F + f], w1 = o1w[(c + 1) * F + f];
        float w2 = o1w[(c + 2) * F + f], w3 = o1w[(c + 3) * F + f];
        #pragma unroll
        for (int i = 0; i < 16; ++i) {
            const float4 s4 = *reinterpret_cast<const float4*>(&sagg[p * 16 + i][c]);
            acc[i] = fmaf(s4.x, w0, fmaf(s4.y, w1, fmaf(s4.z, w2, fmaf(s4.w, w3, acc[i]))));
        }
    }
    float b1 = o1b[f];
    #pragma unroll
    for (int i = 0; i < 16; ++i) ssu[p * 16 + i][f] = ssp(acc[i] + b1);
    __syncthreads();

    #pragma unroll
    for (int i = 0; i < 16; ++i) acc[i] = 0.f;
    for (int c = 0; c < F; c += 4) {
        float w0 = o2w[(c + 0) * F + f], w1 = o2w[(c + 1) * F + f];
        float w2 = o2w[(c + 2) * F + f], w3 = o2w[(c + 3) * F + f];
        #pragma unroll
        for (int i = 0; i < 16; ++i) {
            const float4 s4 = *reinterpret_cast<const float4*>(&ssu[p * 16 + i][c]);
            acc[i] = fmaf(s4.x, w0, fmaf(s4.y, w1, fmaf(s4.z, w2, fmaf(s4.w, w3, acc[i]))));
        }
    }
    float b2 = o2b[f];
    for (int i = 0; i < 16; ++i) {
        int n = a0 + p * 16 + i;
        if (n < N) out[n * F + f] = embed[Z[n] * F + f] + acc[i] + b2;
    }
}

extern "C" void kernel_launch(void* const* d_in, const int* in_sizes, int n_in,
                              void* d_out, int out_size, void* d_ws, size_t ws_size,
                              hipStream_t stream) {
    const float* dR    = (const float*)d_in[0];
    const int*   Z     = (const int*)  d_in[1];
    const int*   nbr   = (const int*)  d_in[2];
    const float* embed = (const float*)d_in[3];
    const float* in2f  = (const float*)d_in[4];
    const float* f1w   = (const float*)d_in[5];
    const float* f1b   = (const float*)d_in[6];
    const float* f2w   = (const float*)d_in[7];
    const float* f2b   = (const float*)d_in[8];
    const float* o1w   = (const float*)d_in[9];
    const float* o1b   = (const float*)d_in[10];
    const float* o2w   = (const float*)d_in[11];
    const float* o2b   = (const float*)d_in[12];

    int N = in_sizes[1];
    float*          y      = (float*)d_ws;                                   // N*128 f32
    unsigned short* f1frag = (unsigned short*)((char*)d_ws + (size_t)N * F * 4);
    unsigned short* f2frag = f1frag + 4096;                                  // +32KB

    k_prep<<<80, 256, 0, stream>>>(f1w, f2w, f1frag, f2frag);
    k_proj_y<<<N, 128, 0, stream>>>(embed, Z, in2f, y, N);
    k_pair<<<N, 256, 0, stream>>>(dR, nbr, y, f1frag, f2frag, f1b, f2b,
                                  (float*)d_out, N);
    k_out<<<(N + 31) / 32, 256, 0, stream>>>(o1w, o1b, o2w, o2b, embed, Z,
                                             (float*)d_out, N);
}

// Round 3
// 151.643 us; speedup vs baseline: 6.9420x; 1.4775x over previous
//
#include <hip/hip_runtime.h>
#include <math.h>

constexpr int F  = 128;
constexpr int KN = 48;
constexpr int NG = 25;
constexpr int TN = 256;          // table intervals; 257 nodes, h = 5/256

__device__ __forceinline__ float ssp(float x) {
    // softplus(x) - ln2 = max(x,0) + log(0.5*exp(-|x|) + 0.5)
    return fmaxf(x, 0.0f) + __logf(fmaf(0.5f, __expf(-fabsf(x)), 0.5f));
}

__device__ __forceinline__ unsigned int f2bf(float x) {
    unsigned int u = __float_as_uint(x);
    return (u + 0x7FFFu + ((u >> 16) & 1u)) >> 16;   // RNE bf16 (as low 16 bits)
}
__device__ __forceinline__ float lo2f(unsigned int w) { return __uint_as_float(w << 16); }
__device__ __forceinline__ float hi2f(unsigned int w) { return __uint_as_float(w & 0xFFFF0000u); }

// ---- Build T[j][f] = (ssp(g(d_j)@f1w + f1b) @ f2w + f2b) * cut(d_j), fp32 ----
// 257 nodes, d_j = j*5/256. One block per node, 128 threads.
__global__ __launch_bounds__(128) void k_table(
    const float* __restrict__ f1w, const float* __restrict__ f1b,
    const float* __restrict__ f2w, const float* __restrict__ f2b,
    float* __restrict__ T)
{
    int j = blockIdx.x;
    int f = threadIdx.x;
    float d = (float)j * (5.0f / 256.0f);

    constexpr float width = 5.0f / 24.0f;
    constexpr float coeff = -0.5f / (width * width);

    float z = f1b[f];
    #pragma unroll
    for (int c = 0; c < NG; ++c) {
        float t = d - (float)c * width;
        float g = __expf(coeff * t * t);
        z = fmaf(g, f1w[c * F + f], z);
    }
    __shared__ float sh[F];
    sh[f] = ssp(z);
    __syncthreads();

    float w = f2b[f];
    #pragma unroll 8
    for (int c = 0; c < F; ++c)
        w = fmaf(sh[c], f2w[c * F + f], w);

    float cut = 0.5f * (cosf(d * 0.62831853071795864769f) + 1.0f);
    cut = (d < 5.0f) ? cut : 0.0f;
    T[j * F + f] = w * cut;
}

// ---- y2 packed: y2[n][l] = bf16(y[n][l]) | bf16(y[n][l+64])<<16 ; row N = 0 ----
// 32 atoms per block, 256 threads.
__global__ __launch_bounds__(256) void k_proj_y2(
    const float* __restrict__ embed, const int* __restrict__ Z,
    const float* __restrict__ in2f_w, unsigned int* __restrict__ y2, int N)
{
    int a0  = blockIdx.x * 32;
    int tid = threadIdx.x;
    int p   = tid >> 7;
    int f   = tid & 127;
    __shared__ float sx[32][F];
    __shared__ float sy[32][F];

    for (int a = p; a < 32; a += 2) {
        int n = a0 + a;
        sx[a][f] = (n < N) ? embed[Z[n] * F + f] : 0.f;
    }
    __syncthreads();

    float acc[16];
    #pragma unroll
    for (int i = 0; i < 16; ++i) acc[i] = 0.f;
    for (int c = 0; c < F; c += 4) {
        float w0 = in2f_w[(c + 0) * F + f], w1 = in2f_w[(c + 1) * F + f];
        float w2 = in2f_w[(c + 2) * F + f], w3 = in2f_w[(c + 3) * F + f];
        #pragma unroll
        for (int i = 0; i < 16; ++i) {
            const float4 s4 = *reinterpret_cast<const float4*>(&sx[p * 16 + i][c]);
            acc[i] = fmaf(s4.x, w0, fmaf(s4.y, w1, fmaf(s4.z, w2, fmaf(s4.w, w3, acc[i]))));
        }
    }
    #pragma unroll
    for (int i = 0; i < 16; ++i) sy[p * 16 + i][f] = acc[i];
    __syncthreads();

    // pack 32*64 words, 8 per thread
    for (int t = 0; t < 8; ++t) {
        int m  = tid + t * 256;
        int a  = m >> 6, fl = m & 63;
        int n  = a0 + a;
        if (n < N)
            y2[n * 64 + fl] = f2bf(sy[a][fl]) | (f2bf(sy[a][fl + 64]) << 16);
        else if (n == N)
            y2[n * 64 + fl] = 0u;     // padding row
    }
}

// ---- Core: per pair, lerp table + gather y, aggregate. One atom per wave. ----
// 1024 threads = 16 waves; dynamic LDS = 128 KiB pair-packed bf16 table:
//   tab[j*128+f] = bf16(T[j][f]) | bf16(T[j+1][f])<<16
__global__ __launch_bounds__(1024) void k_pairagg(
    const float* __restrict__ dR, const int* __restrict__ nbr,
    const float* __restrict__ T, const unsigned int* __restrict__ y2,
    float* __restrict__ agg_out, int N)
{
    extern __shared__ unsigned int tab[];   // 256*128 u32 = 128 KiB
    int tid = threadIdx.x;

    // stage + pack table: 32768 words, 32 per thread; lo=T[m], hi=T[m+128]
    for (int t = 0; t < 32; ++t) {
        int m = tid + t * 1024;
        tab[m] = f2bf(T[m]) | (f2bf(T[m + 128]) << 16);
    }
    __syncthreads();

    int wid  = tid >> 6;
    int lane = tid & 63;

    for (int it = 0; it < 4; ++it) {
        int n = blockIdx.x * 64 + it * 16 + wid;
        if (n >= N) continue;

        float d = 0.f; int idx = N;
        if (lane < KN) {
            d   = dR[n * KN + lane];
            idx = nbr[n * KN + lane];
            if (idx > N) idx = N;           // safety; padding row is zero
        }
        float u  = d * 51.2f;               // 256/5
        int   j  = (int)u; j = (j > 255) ? 255 : j;
        float fr = u - (float)j;
        int   jw = j << 7;                  // word offset of table row
        int   yb = idx << 6;                // word offset of packed y row

        float acc0 = 0.f, acc1 = 0.f;
        #pragma unroll 8
        for (int k = 0; k < KN; ++k) {
            int   jwk = __shfl(jw, k);
            float frk = __shfl(fr, k);
            int   ybk = __shfl(yb, k);
            unsigned int tA = tab[jwk + lane];
            unsigned int tB = tab[jwk + lane + 64];
            unsigned int yw = y2[ybk + lane];
            float a0 = lo2f(tA), b0 = hi2f(tA);
            float a1 = lo2f(tB), b1 = hi2f(tB);
            float w0 = fmaf(frk, b0 - a0, a0);
            float w1 = fmaf(frk, b1 - a1, a1);
            acc0 = fmaf(w0, lo2f(yw), acc0);
            acc1 = fmaf(w1, hi2f(yw), acc1);
        }
        agg_out[n * F + lane]      = acc0;
        agg_out[n * F + 64 + lane] = acc1;
    }
}

// ---- Output network (fp32, 32 atoms/block); agg in `out`, overwritten ----
__global__ __launch_bounds__(256) void k_out(
    const float* __restrict__ o1w, const float* __restrict__ o1b,
    const float* __restrict__ o2w, const float* __restrict__ o2b,
    const float* __restrict__ embed, const int* __restrict__ Z,
    float* __restrict__ out, int N)
{
    int a0  = blockIdx.x * 32;
    int tid = threadIdx.x;
    int p   = tid >> 7;
    int f   = tid & 127;
    __shared__ float sagg[32][F];
    __shared__ float ssu[32][F];

    for (int a = p; a < 32; a += 2) {
        int n = a0 + a;
        sagg[a][f] = (n < N) ? out[n * F + f] : 0.f;
    }
    __syncthreads();

    float acc[16];
    #pragma unroll
    for (int i = 0; i < 16; ++i) acc[i] = 0.f;
    for (int c = 0; c < F; c += 4) {
        float w0 = o1w[(c + 0) * F + f], w1 = o1w[(c + 1) * F + f];
        float w2 = o1w[(c + 2) * F + f], w3 = o1w[(c + 3) * F + f];
        #pragma unroll
        for (int i = 0; i < 16; ++i) {
            const float4 s4 = *reinterpret_cast<const float4*>(&sagg[p * 16 + i][c]);
            acc[i] = fmaf(s4.x, w0, fmaf(s4.y, w1, fmaf(s4.z, w2, fmaf(s4.w, w3, acc[i]))));
        }
    }
    float b1 = o1b[f];
    #pragma unroll
    for (int i = 0; i < 16; ++i) ssu[p * 16 + i][f] = ssp(acc[i] + b1);
    __syncthreads();

    #pragma unroll
    for (int i = 0; i < 16; ++i) acc[i] = 0.f;
    for (int c = 0; c < F; c += 4) {
        float w0 = o2w[(c + 0) * F + f], w1 = o2w[(c + 1) * F + f];
        float w2 = o2w[(c + 2) * F + f], w3 = o2w[(c + 3) * F + f];
        #pragma unroll
        for (int i = 0; i < 16; ++i) {
            const float4 s4 = *reinterpret_cast<const float4*>(&ssu[p * 16 + i][c]);
            acc[i] = fmaf(s4.x, w0, fmaf(s4.y, w1, fmaf(s4.z, w2, fmaf(s4.w, w3, acc[i]))));
        }
    }
    float b2 = o2b[f];
    for (int i = 0; i < 16; ++i) {
        int n = a0 + p * 16 + i;
        if (n < N) out[n * F + f] = embed[Z[n] * F + f] + acc[i] + b2;
    }
}

extern "C" void kernel_launch(void* const* d_in, const int* in_sizes, int n_in,
                              void* d_out, int out_size, void* d_ws, size_t ws_size,
                              hipStream_t stream) {
    const float* dR    = (const float*)d_in[0];
    const int*   Z     = (const int*)  d_in[1];
    const int*   nbr   = (const int*)  d_in[2];
    const float* embed = (const float*)d_in[3];
    const float* in2f  = (const float*)d_in[4];
    const float* f1w   = (const float*)d_in[5];
    const float* f1b   = (const float*)d_in[6];
    const float* f2w   = (const float*)d_in[7];
    const float* f2b   = (const float*)d_in[8];
    const float* o1w   = (const float*)d_in[9];
    const float* o1b   = (const float*)d_in[10];
    const float* o2w   = (const float*)d_in[11];
    const float* o2b   = (const float*)d_in[12];

    int N = in_sizes[1];
    unsigned int* y2 = (unsigned int*)d_ws;                        // (N+1)*64 u32
    float*        T  = (float*)((char*)d_ws + (size_t)(N + 1) * 64 * 4);  // 257*128 f32

    (void)hipFuncSetAttribute((const void*)k_pairagg,
                              hipFuncAttributeMaxDynamicSharedMemorySize, 131072);

    k_table<<<TN + 1, 128, 0, stream>>>(f1w, f1b, f2w, f2b, T);
    k_proj_y2<<<(N + 32) / 32, 256, 0, stream>>>(embed, Z, in2f, y2, N);
    k_pairagg<<<(N + 63) / 64, 1024, 131072, stream>>>(dR, nbr, T, y2,
                                                       (float*)d_out, N);
    k_out<<<(N + 31) / 32, 256, 0, stream>>>(o1w, o1b, o2w, o2b, embed, Z,
                                             (float*)d_out, N);
}

// Round 4
// 146.635 us; speedup vs baseline: 7.1791x; 1.0342x over previous
//
#include <hip/hip_runtime.h>
#include <math.h>

constexpr int F  = 128;
constexpr int KN = 48;
constexpr int NG = 25;
constexpr int TN = 256;          // table intervals; 257 nodes, h = 5/256

__device__ __forceinline__ float ssp(float x) {
    // softplus(x) - ln2 = max(x,0) + log(0.5*exp(-|x|) + 0.5)
    return fmaxf(x, 0.0f) + __logf(fmaf(0.5f, __expf(-fabsf(x)), 0.5f));
}

__device__ __forceinline__ unsigned int f2bf(float x) {
    unsigned int u = __float_as_uint(x);
    return (u + 0x7FFFu + ((u >> 16) & 1u)) >> 16;   // RNE bf16 (low 16 bits)
}
__device__ __forceinline__ float lo2f(unsigned int w) { return __uint_as_float(w << 16); }
__device__ __forceinline__ float hi2f(unsigned int w) { return __uint_as_float(w & 0xFFFF0000u); }

// ---- Build T[j][f] = (ssp(g(d_j)@f1w + f1b) @ f2w + f2b) * cut(d_j), fp32 ----
__global__ __launch_bounds__(128) void k_table(
    const float* __restrict__ f1w, const float* __restrict__ f1b,
    const float* __restrict__ f2w, const float* __restrict__ f2b,
    float* __restrict__ T)
{
    int j = blockIdx.x;
    int f = threadIdx.x;
    float d = (float)j * (5.0f / 256.0f);

    constexpr float width = 5.0f / 24.0f;
    constexpr float coeff = -0.5f / (width * width);

    float z = f1b[f];
    #pragma unroll
    for (int c = 0; c < NG; ++c) {
        float t = d - (float)c * width;
        float g = __expf(coeff * t * t);
        z = fmaf(g, f1w[c * F + f], z);
    }
    __shared__ float sh[F];
    sh[f] = ssp(z);
    __syncthreads();

    float w = f2b[f];
    #pragma unroll 8
    for (int c = 0; c < F; ++c)
        w = fmaf(sh[c], f2w[c * F + f], w);

    float cut = 0.5f * (cosf(d * 0.62831853071795864769f) + 1.0f);
    cut = (d < 5.0f) ? cut : 0.0f;
    T[j * F + f] = w * cut;
}

// ---- y2 packed adjacent: y2[n][l] = bf16(y[n][2l]) | bf16(y[n][2l+1])<<16 ----
__global__ __launch_bounds__(256) void k_proj_y2(
    const float* __restrict__ embed, const int* __restrict__ Z,
    const float* __restrict__ in2f_w, unsigned int* __restrict__ y2, int N)
{
    int a0  = blockIdx.x * 32;
    int tid = threadIdx.x;
    int p   = tid >> 7;
    int f   = tid & 127;
    __shared__ float sx[32][F];
    __shared__ float sy[32][F];

    for (int a = p; a < 32; a += 2) {
        int n = a0 + a;
        sx[a][f] = (n < N) ? embed[Z[n] * F + f] : 0.f;
    }
    __syncthreads();

    float acc[16];
    #pragma unroll
    for (int i = 0; i < 16; ++i) acc[i] = 0.f;
    for (int c = 0; c < F; c += 4) {
        float w0 = in2f_w[(c + 0) * F + f], w1 = in2f_w[(c + 1) * F + f];
        float w2 = in2f_w[(c + 2) * F + f], w3 = in2f_w[(c + 3) * F + f];
        #pragma unroll
        for (int i = 0; i < 16; ++i) {
            const float4 s4 = *reinterpret_cast<const float4*>(&sx[p * 16 + i][c]);
            acc[i] = fmaf(s4.x, w0, fmaf(s4.y, w1, fmaf(s4.z, w2, fmaf(s4.w, w3, acc[i]))));
        }
    }
    #pragma unroll
    for (int i = 0; i < 16; ++i) sy[p * 16 + i][f] = acc[i];
    __syncthreads();

    for (int t = 0; t < 8; ++t) {
        int m  = tid + t * 256;
        int a  = m >> 6, fl = m & 63;
        int n  = a0 + a;
        if (n < N)
            y2[n * 64 + fl] = f2bf(sy[a][2 * fl]) | (f2bf(sy[a][2 * fl + 1]) << 16);
        else if (n == N)
            y2[n * 64 + fl] = 0u;     // padding row
    }
}

// ---- Core: lerp table + gather, one atom per wave, 2 atoms in flight (ILP2) ----
// dynamic LDS 64.25 KiB: tabw[j*64+l] = bf16(T[j][2l]) | bf16(T[j][2l+1])<<16,
// j = 0..256. Lerp reads rows j and j+1 (offset 64 words -> ds_read2_b32).
__global__ __launch_bounds__(1024, 8) void k_pairagg(
    const float* __restrict__ dR, const int* __restrict__ nbr,
    const float* __restrict__ T, const unsigned int* __restrict__ y2,
    float* __restrict__ agg_out, int N)
{
    extern __shared__ unsigned int tabw[];   // 257*64 u32 = 65792 B
    int tid = threadIdx.x;

    const float2* T2 = (const float2*)T;
    for (int m = tid; m < 257 * 64; m += 1024) {
        float2 v = T2[m];
        tabw[m] = f2bf(v.x) | (f2bf(v.y) << 16);
    }
    __syncthreads();

    int wid  = tid >> 6;
    int lane = tid & 63;

    #pragma unroll
    for (int it = 0; it < 2; ++it) {
        int nA = blockIdx.x * 64 + it * 32 + wid;
        int nB = nA + 16;
        bool vA = nA < N, vB = nB < N;
        if (!vA) break;
        int nAs = nA, nBs = vB ? nB : nA;

        // per-lane pair params for both atoms
        int jwA = 0, ybA = 0; float frA = 0.f;
        int jwB = 0, ybB = 0; float frB = 0.f;
        if (lane < KN) {
            float dA = dR[nAs * KN + lane];
            int   iA = nbr[nAs * KN + lane];
            if (iA > N) iA = N;
            float uA = dA * 51.2f;
            int   jA = (int)uA; jA = (jA > 255) ? 255 : jA;
            frA = uA - (float)jA;
            jwA = jA << 6;
            ybA = iA << 6;

            float dB = dR[nBs * KN + lane];
            int   iB = nbr[nBs * KN + lane];
            if (iB > N) iB = N;
            float uB = dB * 51.2f;
            int   jB = (int)uB; jB = (jB > 255) ? 255 : jB;
            frB = uB - (float)jB;
            jwB = jB << 6;
            ybB = iB << 6;
        }

        float a0 = 0.f, a1 = 0.f, b0 = 0.f, b1 = 0.f;
        #pragma unroll 8
        for (int k = 0; k < KN; ++k) {
            int   jA = __shfl(jwA, k);
            float fA = __shfl(frA, k);
            int   yA = __shfl(ybA, k);
            int   jB = __shfl(jwB, k);
            float fB = __shfl(frB, k);
            int   yB = __shfl(ybB, k);

            unsigned int wA0 = tabw[jA + lane];
            unsigned int wA1 = tabw[jA + lane + 64];
            unsigned int ywA = y2[yA + lane];
            unsigned int wB0 = tabw[jB + lane];
            unsigned int wB1 = tabw[jB + lane + 64];
            unsigned int ywB = y2[yB + lane];

            float tA0 = lo2f(wA0), tA1 = hi2f(wA0);
            float sA0 = lo2f(wA1), sA1 = hi2f(wA1);
            float vA0 = fmaf(fA, sA0 - tA0, tA0);
            float vA1 = fmaf(fA, sA1 - tA1, tA1);
            a0 = fmaf(vA0, lo2f(ywA), a0);
            a1 = fmaf(vA1, hi2f(ywA), a1);

            float tB0 = lo2f(wB0), tB1 = hi2f(wB0);
            float sB0 = lo2f(wB1), sB1 = hi2f(wB1);
            float vB0 = fmaf(fB, sB0 - tB0, tB0);
            float vB1 = fmaf(fB, sB1 - tB1, tB1);
            b0 = fmaf(vB0, lo2f(ywB), b0);
            b1 = fmaf(vB1, hi2f(ywB), b1);
        }

        float2* o = (float2*)agg_out;
        o[nAs * 64 + lane] = make_float2(a0, a1);
        if (vB) o[nB * 64 + lane] = make_float2(b0, b1);
    }
}

// ---- Output network (fp32, 32 atoms/block); agg in `out`, overwritten ----
__global__ __launch_bounds__(256) void k_out(
    const float* __restrict__ o1w, const float* __restrict__ o1b,
    const float* __restrict__ o2w, const float* __restrict__ o2b,
    const float* __restrict__ embed, const int* __restrict__ Z,
    float* __restrict__ out, int N)
{
    int a0  = blockIdx.x * 32;
    int tid = threadIdx.x;
    int p   = tid >> 7;
    int f   = tid & 127;
    __shared__ float sagg[32][F];
    __shared__ float ssu[32][F];

    for (int a = p; a < 32; a += 2) {
        int n = a0 + a;
        sagg[a][f] = (n < N) ? out[n * F + f] : 0.f;
    }
    __syncthreads();

    float acc[16];
    #pragma unroll
    for (int i = 0; i < 16; ++i) acc[i] = 0.f;
    for (int c = 0; c < F; c += 4) {
        float w0 = o1w[(c + 0) * F + f], w1 = o1w[(c + 1) * F + f];
        float w2 = o1w[(c + 2) * F + f], w3 = o1w[(c + 3) * F + f];
        #pragma unroll
        for (int i = 0; i < 16; ++i) {
            const float4 s4 = *reinterpret_cast<const float4*>(&sagg[p * 16 + i][c]);
            acc[i] = fmaf(s4.x, w0, fmaf(s4.y, w1, fmaf(s4.z, w2, fmaf(s4.w, w3, acc[i]))));
        }
    }
    float b1 = o1b[f];
    #pragma unroll
    for (int i = 0; i < 16; ++i) ssu[p * 16 + i][f] = ssp(acc[i] + b1);
    __syncthreads();

    #pragma unroll
    for (int i = 0; i < 16; ++i) acc[i] = 0.f;
    for (int c = 0; c < F; c += 4) {
        float w0 = o2w[(c + 0) * F + f], w1 = o2w[(c + 1) * F + f];
        float w2 = o2w[(c + 2) * F + f], w3 = o2w[(c + 3) * F + f];
        #pragma unroll
        for (int i = 0; i < 16; ++i) {
            const float4 s4 = *reinterpret_cast<const float4*>(&ssu[p * 16 + i][c]);
            acc[i] = fmaf(s4.x, w0, fmaf(s4.y, w1, fmaf(s4.z, w2, fmaf(s4.w, w3, acc[i]))));
        }
    }
    float b2 = o2b[f];
    for (int i = 0; i < 16; ++i) {
        int n = a0 + p * 16 + i;
        if (n < N) out[n * F + f] = embed[Z[n] * F + f] + acc[i] + b2;
    }
}

extern "C" void kernel_launch(void* const* d_in, const int* in_sizes, int n_in,
                              void* d_out, int out_size, void* d_ws, size_t ws_size,
                              hipStream_t stream) {
    const float* dR    = (const float*)d_in[0];
    const int*   Z     = (const int*)  d_in[1];
    const int*   nbr   = (const int*)  d_in[2];
    const float* embed = (const float*)d_in[3];
    const float* in2f  = (const float*)d_in[4];
    const float* f1w   = (const float*)d_in[5];
    const float* f1b   = (const float*)d_in[6];
    const float* f2w   = (const float*)d_in[7];
    const float* f2b   = (const float*)d_in[8];
    const float* o1w   = (const float*)d_in[9];
    const float* o1b   = (const float*)d_in[10];
    const float* o2w   = (const float*)d_in[11];
    const float* o2b   = (const float*)d_in[12];

    int N = in_sizes[1];
    unsigned int* y2 = (unsigned int*)d_ws;                               // (N+1)*64 u32
    float*        T  = (float*)((char*)d_ws + (size_t)(N + 1) * 64 * 4); // 257*128 f32

    (void)hipFuncSetAttribute((const void*)k_pairagg,
                              hipFuncAttributeMaxDynamicSharedMemorySize, 65792);

    k_table<<<TN + 1, 128, 0, stream>>>(f1w, f1b, f2w, f2b, T);
    k_proj_y2<<<(N + 32) / 32, 256, 0, stream>>>(embed, Z, in2f, y2, N);
    k_pairagg<<<(N + 63) / 64, 1024, 65792, stream>>>(dR, nbr, T, y2,
                                                      (float*)d_out, N);
    k_out<<<(N + 31) / 32, 256, 0, stream>>>(o1w, o1b, o2w, o2b, embed, Z,
                                             (float*)d_out, N);
}

// Round 5
// 109.477 us; speedup vs baseline: 9.6158x; 1.3394x over previous
//
#include <hip/hip_runtime.h>
#include <math.h>

constexpr int F   = 128;
constexpr int KN  = 48;
constexpr int NG  = 25;
constexpr int TN  = 512;          // table intervals; 513 nodes, h = 5/512
constexpr int MAXZ = 100;

__device__ __forceinline__ float ssp(float x) {
    // softplus(x) - ln2 = max(x,0) + log(0.5*exp(-|x|) + 0.5)
    return fmaxf(x, 0.0f) + __logf(fmaf(0.5f, __expf(-fabsf(x)), 0.5f));
}

__device__ __forceinline__ unsigned int f2bf(float x) {
    unsigned int u = __float_as_uint(x);
    return (u + 0x7FFFu + ((u >> 16) & 1u)) >> 16;   // RNE bf16 (low 16 bits)
}
__device__ __forceinline__ float lo2f(unsigned int w) { return __uint_as_float(w << 16); }
__device__ __forceinline__ float hi2f(unsigned int w) { return __uint_as_float(w & 0xFFFF0000u); }

// ---- T[j][f] = (ssp(g(d_j)@f1w + f1b) @ f2w + f2b) * cut(d_j), fp32, 513 rows ----
__global__ __launch_bounds__(128) void k_table(
    const float* __restrict__ f1w, const float* __restrict__ f1b,
    const float* __restrict__ f2w, const float* __restrict__ f2b,
    float* __restrict__ T)
{
    int j = blockIdx.x;
    int f = threadIdx.x;
    float d = (float)j * (5.0f / (float)TN);

    constexpr float width = 5.0f / 24.0f;
    constexpr float coeff = -0.5f / (width * width);

    float z = f1b[f];
    #pragma unroll
    for (int c = 0; c < NG; ++c) {
        float t = d - (float)c * width;
        float g = __expf(coeff * t * t);
        z = fmaf(g, f1w[c * F + f], z);
    }
    __shared__ float sh[F];
    sh[f] = ssp(z);
    __syncthreads();

    float w = f2b[f];
    #pragma unroll 8
    for (int c = 0; c < F; ++c)
        w = fmaf(sh[c], f2w[c * F + f], w);

    float cut = 0.5f * (cosf(d * 0.62831853071795864769f) + 1.0f);
    cut = (d < 5.0f) ? cut : 0.0f;
    T[j * F + f] = w * cut;
}

// ---- pack rows (j, j+1) bf16: tabg[j*64+l] = {pk(Tj[2l],Tj[2l+1]), pk(Tj+1[..])} ----
__global__ __launch_bounds__(256) void k_packtab(
    const float* __restrict__ T, uint2* __restrict__ tabg)
{
    int e = blockIdx.x * 256 + threadIdx.x;
    if (e >= TN * 64) return;
    int j = e >> 6, l = (e & 63) * 2;
    const float* r0 = T + j * F;
    const float* r1 = r0 + F;
    tabg[e] = make_uint2(f2bf(r0[l]) | (f2bf(r0[l + 1]) << 16),
                         f2bf(r1[l]) | (f2bf(r1[l + 1]) << 16));
}

// ---- yzp[z][l] = pack(yz[z][2l], yz[z][2l+1]), yz = embed @ in2f; row MAXZ = 0 ----
__global__ __launch_bounds__(128) void k_embedproj(
    const float* __restrict__ embed, const float* __restrict__ in2f_w,
    unsigned int* __restrict__ yzp)
{
    int z = blockIdx.x;          // 0..MAXZ
    int f = threadIdx.x;
    __shared__ float sx[F];
    __shared__ float row[F];
    if (z < MAXZ) {
        sx[f] = embed[z * F + f];
        __syncthreads();
        float acc = 0.f;
        #pragma unroll 8
        for (int c = 0; c < F; ++c)
            acc = fmaf(sx[c], in2f_w[c * F + f], acc);
        row[f] = acc;
    } else {
        row[f] = 0.f;
    }
    __syncthreads();
    if (f < 64)
        yzp[z * 64 + f] = f2bf(row[2 * f]) | (f2bf(row[2 * f + 1]) << 16);
}

// ---- per-pair params: (fr16<<16) | (j<<7) | zidx ----
__global__ __launch_bounds__(256) void k_params(
    const float* __restrict__ dR, const int* __restrict__ nbr,
    const int* __restrict__ Z, unsigned int* __restrict__ params, int N)
{
    int e = blockIdx.x * 256 + threadIdx.x;
    if (e >= N * KN) return;
    float d = dR[e];
    int   i = nbr[e];
    float u = d * ((float)TN / 5.0f);
    int   j = (int)u; j = (j > TN - 1) ? (TN - 1) : j;
    float fr = u - (float)j;
    unsigned int fr16 = (unsigned int)(fr * 65536.0f);
    if (fr16 > 65535u) fr16 = 65535u;
    unsigned int z = (i >= 0 && i < N) ? (unsigned int)Z[i] : (unsigned int)MAXZ;
    params[e] = (fr16 << 16) | ((unsigned int)j << 7) | z;
}

// ---- Core: 2 atoms per wave, 4 waves per block, no LDS. Params via scalar
//      loads (readfirstlane'd base); table/yz gathers from L1/L2-hot globals. ----
__global__ __launch_bounds__(256, 8) void k_pairagg(
    const unsigned int* __restrict__ params,
    const uint2* __restrict__ tabg,
    const unsigned int* __restrict__ yzp,
    float2* __restrict__ agg_out, int N)
{
    int tid  = threadIdx.x;
    int wid  = tid >> 6;
    int lane = tid & 63;
    int nA = blockIdx.x * 8 + wid * 2;
    int nB = nA + 1;
    if (nA >= N) return;
    bool vB = (nB < N);
    int baseA = __builtin_amdgcn_readfirstlane(nA) * KN;
    int baseB = __builtin_amdgcn_readfirstlane(vB ? nB : nA) * KN;

    float a0 = 0.f, a1 = 0.f, b0 = 0.f, b1 = 0.f;
    #pragma unroll 4
    for (int k = 0; k < KN; ++k) {
        unsigned int pA = params[baseA + k];
        unsigned int pB = params[baseB + k];

        float frA = (float)(pA >> 16) * (1.0f / 65536.0f);
        uint2 tA  = tabg[(int)(((pA >> 7) & 0x1FFu) << 6) + lane];
        unsigned int yA = yzp[(int)((pA & 0x7Fu) << 6) + lane];

        float frB = (float)(pB >> 16) * (1.0f / 65536.0f);
        uint2 tB  = tabg[(int)(((pB >> 7) & 0x1FFu) << 6) + lane];
        unsigned int yB = yzp[(int)((pB & 0x7Fu) << 6) + lane];

        float tA0 = lo2f(tA.x), tA1 = hi2f(tA.x);
        float sA0 = lo2f(tA.y), sA1 = hi2f(tA.y);
        float wA0 = fmaf(frA, sA0 - tA0, tA0);
        float wA1 = fmaf(frA, sA1 - tA1, tA1);
        a0 = fmaf(wA0, lo2f(yA), a0);
        a1 = fmaf(wA1, hi2f(yA), a1);

        float tB0 = lo2f(tB.x), tB1 = hi2f(tB.x);
        float sB0 = lo2f(tB.y), sB1 = hi2f(tB.y);
        float wB0 = fmaf(frB, sB0 - tB0, tB0);
        float wB1 = fmaf(frB, sB1 - tB1, tB1);
        b0 = fmaf(wB0, lo2f(yB), b0);
        b1 = fmaf(wB1, hi2f(yB), b1);
    }

    agg_out[nA * 64 + lane] = make_float2(a0, a1);
    if (vB) agg_out[nB * 64 + lane] = make_float2(b0, b1);
}

// ---- Output network (fp32, 32 atoms/block); agg in `out`, overwritten ----
__global__ __launch_bounds__(256) void k_out(
    const float* __restrict__ o1w, const float* __restrict__ o1b,
    const float* __restrict__ o2w, const float* __restrict__ o2b,
    const float* __restrict__ embed, const int* __restrict__ Z,
    float* __restrict__ out, int N)
{
    int a0  = blockIdx.x * 32;
    int tid = threadIdx.x;
    int p   = tid >> 7;
    int f   = tid & 127;
    __shared__ float sagg[32][F];
    __shared__ float ssu[32][F];

    for (int a = p; a < 32; a += 2) {
        int n = a0 + a;
        sagg[a][f] = (n < N) ? out[n * F + f] : 0.f;
    }
    __syncthreads();

    float acc[16];
    #pragma unroll
    for (int i = 0; i < 16; ++i) acc[i] = 0.f;
    for (int c = 0; c < F; c += 4) {
        float w0 = o1w[(c + 0) * F + f], w1 = o1w[(c + 1) * F + f];
        float w2 = o1w[(c + 2) * F + f], w3 = o1w[(c + 3) * F + f];
        #pragma unroll
        for (int i = 0; i < 16; ++i) {
            const float4 s4 = *reinterpret_cast<const float4*>(&sagg[p * 16 + i][c]);
            acc[i] = fmaf(s4.x, w0, fmaf(s4.y, w1, fmaf(s4.z, w2, fmaf(s4.w, w3, acc[i]))));
        }
    }
    float b1 = o1b[f];
    #pragma unroll
    for (int i = 0; i < 16; ++i) ssu[p * 16 + i][f] = ssp(acc[i] + b1);
    __syncthreads();

    #pragma unroll
    for (int i = 0; i < 16; ++i) acc[i] = 0.f;
    for (int c = 0; c < F; c += 4) {
        float w0 = o2w[(c + 0) * F + f], w1 = o2w[(c + 1) * F + f];
        float w2 = o2w[(c + 2) * F + f], w3 = o2w[(c + 3) * F + f];
        #pragma unroll
        for (int i = 0; i < 16; ++i) {
            const float4 s4 = *reinterpret_cast<const float4*>(&ssu[p * 16 + i][c]);
            acc[i] = fmaf(s4.x, w0, fmaf(s4.y, w1, fmaf(s4.z, w2, fmaf(s4.w, w3, acc[i]))));
        }
    }
    float b2 = o2b[f];
    for (int i = 0; i < 16; ++i) {
        int n = a0 + p * 16 + i;
        if (n < N) out[n * F + f] = embed[Z[n] * F + f] + acc[i] + b2;
    }
}

extern "C" void kernel_launch(void* const* d_in, const int* in_sizes, int n_in,
                              void* d_out, int out_size, void* d_ws, size_t ws_size,
                              hipStream_t stream) {
    const float* dR    = (const float*)d_in[0];
    const int*   Z     = (const int*)  d_in[1];
    const int*   nbr   = (const int*)  d_in[2];
    const float* embed = (const float*)d_in[3];
    const float* in2f  = (const float*)d_in[4];
    const float* f1w   = (const float*)d_in[5];
    const float* f1b   = (const float*)d_in[6];
    const float* f2w   = (const float*)d_in[7];
    const float* f2b   = (const float*)d_in[8];
    const float* o1w   = (const float*)d_in[9];
    const float* o1b   = (const float*)d_in[10];
    const float* o2w   = (const float*)d_in[11];
    const float* o2b   = (const float*)d_in[12];

    int N = in_sizes[1];

    // ws layout
    char* w = (char*)d_ws;
    unsigned int* params = (unsigned int*)w;                 // N*48 u32      (3.84 MB)
    w += (size_t)N * KN * 4;
    float* T = (float*)w;                                    // 513*128 f32   (262.7 KB)
    w += (size_t)(TN + 1) * F * 4;
    uint2* tabg = (uint2*)w;                                 // 512*64 uint2  (262.1 KB)
    w += (size_t)TN * 64 * 8;
    unsigned int* yzp = (unsigned int*)w;                    // 101*64 u32    (25.9 KB)

    k_table<<<TN + 1, 128, 0, stream>>>(f1w, f1b, f2w, f2b, T);
    k_packtab<<<(TN * 64 + 255) / 256, 256, 0, stream>>>(T, tabg);
    k_embedproj<<<MAXZ + 1, 128, 0, stream>>>(embed, in2f, yzp);
    k_params<<<(N * KN + 255) / 256, 256, 0, stream>>>(dR, nbr, Z, params, N);
    k_pairagg<<<(N + 7) / 8, 256, 0, stream>>>(params, tabg, yzp,
                                               (float2*)d_out, N);
    k_out<<<(N + 31) / 32, 256, 0, stream>>>(o1w, o1b, o2w, o2b, embed, Z,
                                             (float*)d_out, N);
}

// Round 6
// 79.721 us; speedup vs baseline: 13.2049x; 1.3733x over previous
//
#include <hip/hip_runtime.h>
#include <math.h>

constexpr int F    = 128;
constexpr int KN   = 48;
constexpr int NG   = 25;
constexpr int TN   = 512;         // table intervals; 513 nodes, h = 5/512
constexpr int MAXZ = 100;

typedef short bf16x8 __attribute__((ext_vector_type(8)));
typedef float f32x4  __attribute__((ext_vector_type(4)));

__device__ __forceinline__ float ssp(float x) {
    // softplus(x) - ln2 = max(x,0) + log(0.5*exp(-|x|) + 0.5)
    return fmaxf(x, 0.0f) + __logf(fmaf(0.5f, __expf(-fabsf(x)), 0.5f));
}

__device__ __forceinline__ unsigned int f2bf(float x) {
    unsigned int u = __float_as_uint(x);
    return (u + 0x7FFFu + ((u >> 16) & 1u)) >> 16;   // RNE bf16 (low 16 bits)
}
__device__ __forceinline__ float lo2f(unsigned int w) { return __uint_as_float(w << 16); }
__device__ __forceinline__ float hi2f(unsigned int w) { return __uint_as_float(w & 0xFFFF0000u); }

// ---- T[j][f] = (ssp(g(d_j)@f1w + f1b) @ f2w + f2b) * cut(d_j), fp32, 513 rows ----
__global__ __launch_bounds__(128) void k_table(
    const float* __restrict__ f1w, const float* __restrict__ f1b,
    const float* __restrict__ f2w, const float* __restrict__ f2b,
    float* __restrict__ T)
{
    int j = blockIdx.x;
    int f = threadIdx.x;
    float d = (float)j * (5.0f / (float)TN);

    constexpr float width = 5.0f / 24.0f;
    constexpr float coeff = -0.5f / (width * width);

    float z = f1b[f];
    #pragma unroll
    for (int c = 0; c < NG; ++c) {
        float t = d - (float)c * width;
        float g = __expf(coeff * t * t);
        z = fmaf(g, f1w[c * F + f], z);
    }
    __shared__ float sh[F];
    sh[f] = ssp(z);
    __syncthreads();

    float w = f2b[f];
    #pragma unroll 8
    for (int c = 0; c < F; ++c)
        w = fmaf(sh[c], f2w[c * F + f], w);

    float cut = 0.5f * (cosf(d * 0.62831853071795864769f) + 1.0f);
    cut = (d < 5.0f) ? cut : 0.0f;
    T[j * F + f] = w * cut;
}

// ---- pack rows (j, j+1) bf16: tabg[j*64+l] = {pk(Tj[2l],Tj[2l+1]), pk(Tj+1[..])} ----
__global__ __launch_bounds__(256) void k_packtab(
    const float* __restrict__ T, uint2* __restrict__ tabg)
{
    int e = blockIdx.x * 256 + threadIdx.x;
    if (e >= TN * 64) return;
    int j = e >> 6, l = (e & 63) * 2;
    const float* r0 = T + j * F;
    const float* r1 = r0 + F;
    tabg[e] = make_uint2(f2bf(r0[l]) | (f2bf(r0[l + 1]) << 16),
                         f2bf(r1[l]) | (f2bf(r1[l + 1]) << 16));
}

// ---- pre-swizzle o1w/o2w into MFMA B-frag-major bf16 (round-2-verified layout) ----
__global__ __launch_bounds__(256) void k_prepw(
    const float* __restrict__ o1w, const float* __restrict__ o2w,
    unsigned short* __restrict__ o1frag, unsigned short* __restrict__ o2frag)
{
    int t = blockIdx.x * 256 + threadIdx.x;   // 0..32767
    if (t >= 32768) return;
    int e = t & 16383;
    int j = e & 7, l = (e >> 3) & 63, nt = (e >> 9) & 7, kt = e >> 12;
    int k = kt * 32 + ((l >> 4) << 3) + j;
    int col = nt * 16 + (l & 15);
    if (t < 16384) o1frag[e] = (unsigned short)f2bf(o1w[k * F + col]);
    else           o2frag[e] = (unsigned short)f2bf(o2w[k * F + col]);
}

// ---- yzp[z][l] = pack(yz[z][2l], yz[z][2l+1]), yz = embed @ in2f; row MAXZ = 0 ----
__global__ __launch_bounds__(128) void k_embedproj(
    const float* __restrict__ embed, const float* __restrict__ in2f_w,
    unsigned int* __restrict__ yzp)
{
    int z = blockIdx.x;          // 0..MAXZ
    int f = threadIdx.x;
    __shared__ float sx[F];
    __shared__ float row[F];
    if (z < MAXZ) {
        sx[f] = embed[z * F + f];
        __syncthreads();
        float acc = 0.f;
        #pragma unroll 8
        for (int c = 0; c < F; ++c)
            acc = fmaf(sx[c], in2f_w[c * F + f], acc);
        row[f] = acc;
    } else {
        row[f] = 0.f;
    }
    __syncthreads();
    if (f < 64)
        yzp[z * 64 + f] = f2bf(row[2 * f]) | (f2bf(row[2 * f + 1]) << 16);
}

// ---- per-pair params: (fr16<<16) | (j<<7) | zidx ----
__global__ __launch_bounds__(256) void k_params(
    const float* __restrict__ dR, const int* __restrict__ nbr,
    const int* __restrict__ Z, unsigned int* __restrict__ params, int N)
{
    int e = blockIdx.x * 256 + threadIdx.x;
    if (e >= N * KN) return;
    float d = dR[e];
    int   i = nbr[e];
    float u = d * ((float)TN / 5.0f);
    int   j = (int)u; j = (j > TN - 1) ? (TN - 1) : j;
    float fr = u - (float)j;
    unsigned int fr16 = (unsigned int)(fr * 65536.0f);
    if (fr16 > 65535u) fr16 = 65535u;
    unsigned int z = (i >= 0 && i < N) ? (unsigned int)Z[i] : (unsigned int)MAXZ;
    params[e] = (fr16 << 16) | ((unsigned int)j << 7) | z;
}

// ---- Core: 4 atoms per wave (ILP4), no LDS; writes packed-bf16 agg ----
__global__ __launch_bounds__(256, 6) void k_pairagg(
    const unsigned int* __restrict__ params,
    const uint2* __restrict__ tabg,
    const unsigned int* __restrict__ yzp,
    unsigned int* __restrict__ aggb, int N)
{
    int tid  = threadIdx.x;
    int wid  = tid >> 6;
    int lane = tid & 63;
    int n0 = blockIdx.x * 16 + wid * 4;
    if (n0 >= N) return;
    int m1 = (n0 + 1 < N) ? n0 + 1 : n0;
    int m2 = (n0 + 2 < N) ? n0 + 2 : n0;
    int m3 = (n0 + 3 < N) ? n0 + 3 : n0;
    int base0 = __builtin_amdgcn_readfirstlane(n0) * KN;
    int base1 = __builtin_amdgcn_readfirstlane(m1) * KN;
    int base2 = __builtin_amdgcn_readfirstlane(m2) * KN;
    int base3 = __builtin_amdgcn_readfirstlane(m3) * KN;

    float a00 = 0.f, a01 = 0.f, a10 = 0.f, a11 = 0.f;
    float a20 = 0.f, a21 = 0.f, a30 = 0.f, a31 = 0.f;

    #pragma unroll 2
    for (int k = 0; k < KN; ++k) {
        unsigned int p0 = params[base0 + k];
        unsigned int p1 = params[base1 + k];
        unsigned int p2 = params[base2 + k];
        unsigned int p3 = params[base3 + k];

        uint2 t0 = tabg[(int)(((p0 >> 7) & 0x1FFu) << 6) + lane];
        uint2 t1 = tabg[(int)(((p1 >> 7) & 0x1FFu) << 6) + lane];
        uint2 t2 = tabg[(int)(((p2 >> 7) & 0x1FFu) << 6) + lane];
        uint2 t3 = tabg[(int)(((p3 >> 7) & 0x1FFu) << 6) + lane];
        unsigned int y0 = yzp[(int)((p0 & 0x7Fu) << 6) + lane];
        unsigned int y1 = yzp[(int)((p1 & 0x7Fu) << 6) + lane];
        unsigned int y2 = yzp[(int)((p2 & 0x7Fu) << 6) + lane];
        unsigned int y3 = yzp[(int)((p3 & 0x7Fu) << 6) + lane];

        float fr0 = (float)(p0 >> 16) * (1.0f / 65536.0f);
        float fr1 = (float)(p1 >> 16) * (1.0f / 65536.0f);
        float fr2 = (float)(p2 >> 16) * (1.0f / 65536.0f);
        float fr3 = (float)(p3 >> 16) * (1.0f / 65536.0f);

        float w;
        w = fmaf(fr0, lo2f(t0.y) - lo2f(t0.x), lo2f(t0.x)); a00 = fmaf(w, lo2f(y0), a00);
        w = fmaf(fr0, hi2f(t0.y) - hi2f(t0.x), hi2f(t0.x)); a01 = fmaf(w, hi2f(y0), a01);
        w = fmaf(fr1, lo2f(t1.y) - lo2f(t1.x), lo2f(t1.x)); a10 = fmaf(w, lo2f(y1), a10);
        w = fmaf(fr1, hi2f(t1.y) - hi2f(t1.x), hi2f(t1.x)); a11 = fmaf(w, hi2f(y1), a11);
        w = fmaf(fr2, lo2f(t2.y) - lo2f(t2.x), lo2f(t2.x)); a20 = fmaf(w, lo2f(y2), a20);
        w = fmaf(fr2, hi2f(t2.y) - hi2f(t2.x), hi2f(t2.x)); a21 = fmaf(w, hi2f(y2), a21);
        w = fmaf(fr3, lo2f(t3.y) - lo2f(t3.x), lo2f(t3.x)); a30 = fmaf(w, lo2f(y3), a30);
        w = fmaf(fr3, hi2f(t3.y) - hi2f(t3.x), hi2f(t3.x)); a31 = fmaf(w, hi2f(y3), a31);
    }

    aggb[n0 * 64 + lane] = f2bf(a00) | (f2bf(a01) << 16);
    if (n0 + 1 < N) aggb[m1 * 64 + lane] = f2bf(a10) | (f2bf(a11) << 16);
    if (n0 + 2 < N) aggb[m2 * 64 + lane] = f2bf(a20) | (f2bf(a21) << 16);
    if (n0 + 3 < N) aggb[m3 * 64 + lane] = f2bf(a30) | (f2bf(a31) << 16);
}

// ---- Output network via MFMA: 32 atoms/block, 4 waves.
//      out = embed[Z] + ssp(agg@o1+b1)@o2 + b2 ----
__global__ __launch_bounds__(256) void k_outm(
    const unsigned int* __restrict__ aggb,
    const unsigned short* __restrict__ o1frag, const float* __restrict__ o1b,
    const unsigned short* __restrict__ o2frag, const float* __restrict__ o2b,
    const float* __restrict__ embed, const int* __restrict__ Z,
    float* __restrict__ out, int N)
{
    int a0  = blockIdx.x * 32;
    int tid = threadIdx.x;
    int w   = tid >> 6;
    int l   = tid & 63;
    int lr  = l & 15;
    int lg  = l >> 4;

    __shared__ int sZ[32];
    __shared__ __align__(16) unsigned short Us[32 * F];  // bf16 u, XOR-swizzled

    if (tid < 32) {
        int n = a0 + tid;
        sZ[tid] = (n < N) ? Z[n] : 0;
    }

    const unsigned short* aggh = (const unsigned short*)aggb;  // u16 idx = feature

    f32x4 zero = {0.f, 0.f, 0.f, 0.f};
    f32x4 c1[2][2];
    #pragma unroll
    for (int mt = 0; mt < 2; ++mt) { c1[mt][0] = zero; c1[mt][1] = zero; }

    #pragma unroll
    for (int kt = 0; kt < 4; ++kt) {
        bf16x8 b0 = *reinterpret_cast<const bf16x8*>(o1frag + (((kt * 8 + 2 * w + 0) * 64 + l) << 3));
        bf16x8 b1 = *reinterpret_cast<const bf16x8*>(o1frag + (((kt * 8 + 2 * w + 1) * 64 + l) << 3));
        #pragma unroll
        for (int mt = 0; mt < 2; ++mt) {
            int row = a0 + mt * 16 + lr;
            row = (row < N) ? row : N - 1;
            bf16x8 a = *reinterpret_cast<const bf16x8*>(aggh + row * F + kt * 32 + lg * 8);
            c1[mt][0] = __builtin_amdgcn_mfma_f32_16x16x32_bf16(a, b0, c1[mt][0], 0, 0, 0);
            c1[mt][1] = __builtin_amdgcn_mfma_f32_16x16x32_bf16(a, b1, c1[mt][1], 0, 0, 0);
        }
    }

    // epilogue1: u = ssp(t + o1b) -> LDS bf16 swizzled
    #pragma unroll
    for (int ntl = 0; ntl < 2; ++ntl) {
        int fcol = (2 * w + ntl) * 16 + lr;
        float bv = o1b[fcol];
        #pragma unroll
        for (int mt = 0; mt < 2; ++mt) {
            #pragma unroll
            for (int jr = 0; jr < 4; ++jr) {
                int r = mt * 16 + lg * 4 + jr;
                float u = ssp(c1[mt][ntl][jr] + bv);
                Us[r * F + (fcol ^ ((r & 15) << 3))] = (unsigned short)f2bf(u);
            }
        }
    }
    __syncthreads();

    f32x4 c2[2][2];
    #pragma unroll
    for (int mt = 0; mt < 2; ++mt) { c2[mt][0] = zero; c2[mt][1] = zero; }

    #pragma unroll
    for (int kt = 0; kt < 4; ++kt) {
        bf16x8 b0 = *reinterpret_cast<const bf16x8*>(o2frag + (((kt * 8 + 2 * w + 0) * 64 + l) << 3));
        bf16x8 b1 = *reinterpret_cast<const bf16x8*>(o2frag + (((kt * 8 + 2 * w + 1) * 64 + l) << 3));
        #pragma unroll
        for (int mt = 0; mt < 2; ++mt) {
            int r = mt * 16 + lr;
            bf16x8 a = *reinterpret_cast<const bf16x8*>(&Us[r * F + ((kt * 32 + lg * 8) ^ ((r & 15) << 3))]);
            c2[mt][0] = __builtin_amdgcn_mfma_f32_16x16x32_bf16(a, b0, c2[mt][0], 0, 0, 0);
            c2[mt][1] = __builtin_amdgcn_mfma_f32_16x16x32_bf16(a, b1, c2[mt][1], 0, 0, 0);
        }
    }

    // epilogue2: out = embed[Z] + v + o2b
    #pragma unroll
    for (int ntl = 0; ntl < 2; ++ntl) {
        int fcol = (2 * w + ntl) * 16 + lr;
        float bv = o2b[fcol];
        #pragma unroll
        for (int mt = 0; mt < 2; ++mt) {
            #pragma unroll
            for (int jr = 0; jr < 4; ++jr) {
                int r = mt * 16 + lg * 4 + jr;
                int n = a0 + r;
                if (n < N) {
                    float x = embed[sZ[r] * F + fcol];
                    out[n * F + fcol] = x + c2[mt][ntl][jr] + bv;
                }
            }
        }
    }
}

extern "C" void kernel_launch(void* const* d_in, const int* in_sizes, int n_in,
                              void* d_out, int out_size, void* d_ws, size_t ws_size,
                              hipStream_t stream) {
    const float* dR    = (const float*)d_in[0];
    const int*   Z     = (const int*)  d_in[1];
    const int*   nbr   = (const int*)  d_in[2];
    const float* embed = (const float*)d_in[3];
    const float* in2f  = (const float*)d_in[4];
    const float* f1w   = (const float*)d_in[5];
    const float* f1b   = (const float*)d_in[6];
    const float* f2w   = (const float*)d_in[7];
    const float* f2b   = (const float*)d_in[8];
    const float* o1w   = (const float*)d_in[9];
    const float* o1b   = (const float*)d_in[10];
    const float* o2w   = (const float*)d_in[11];
    const float* o2b   = (const float*)d_in[12];

    int N = in_sizes[1];

    // ws layout (all 16B-aligned)
    char* wp = (char*)d_ws;
    unsigned int* params = (unsigned int*)wp;   wp += (size_t)N * KN * 4;      // 3.84 MB
    float*        T      = (float*)wp;          wp += (size_t)(TN + 1) * F * 4;// 262.7 KB
    uint2*        tabg   = (uint2*)wp;          wp += (size_t)TN * 64 * 8;     // 262.1 KB
    unsigned int* yzp    = (unsigned int*)wp;   wp += (size_t)(MAXZ + 1) * 64 * 4; // 25.9 KB
    unsigned short* o1f  = (unsigned short*)wp; wp += 16384 * 2;               // 32 KB
    unsigned short* o2f  = (unsigned short*)wp; wp += 16384 * 2;               // 32 KB
    unsigned int* aggb   = (unsigned int*)wp;                                  // N*64 u32 = 5.12 MB

    k_table<<<TN + 1, 128, 0, stream>>>(f1w, f1b, f2w, f2b, T);
    k_packtab<<<(TN * 64 + 255) / 256, 256, 0, stream>>>(T, tabg);
    k_prepw<<<128, 256, 0, stream>>>(o1w, o2w, o1f, o2f);
    k_embedproj<<<MAXZ + 1, 128, 0, stream>>>(embed, in2f, yzp);
    k_params<<<(N * KN + 255) / 256, 256, 0, stream>>>(dR, nbr, Z, params, N);
    k_pairagg<<<(N + 15) / 16, 256, 0, stream>>>(params, tabg, yzp, aggb, N);
    k_outm<<<(N + 31) / 32, 256, 0, stream>>>(aggb, o1f, o1b, o2f, o2b,
                                              embed, Z, (float*)d_out, N);
}

// Round 7
// 61.735 us; speedup vs baseline: 17.0519x; 1.2913x over previous
//
#include <hip/hip_runtime.h>
#include <math.h>

constexpr int F    = 128;
constexpr int KN   = 48;
constexpr int NG   = 25;
constexpr int TN   = 256;         // table intervals; 257 nodes, h = 5/256
constexpr int MAXZ = 100;

typedef short bf16x8 __attribute__((ext_vector_type(8)));
typedef float f32x4  __attribute__((ext_vector_type(4)));

__device__ __forceinline__ float ssp(float x) {
    // softplus(x) - ln2 = max(x,0) + log(0.5*exp(-|x|) + 0.5)
    return fmaxf(x, 0.0f) + __logf(fmaf(0.5f, __expf(-fabsf(x)), 0.5f));
}

__device__ __forceinline__ unsigned int f2bf(float x) {
    unsigned int u = __float_as_uint(x);
    return (u + 0x7FFFu + ((u >> 16) & 1u)) >> 16;   // RNE bf16 (low 16 bits)
}
__device__ __forceinline__ float lo2f(unsigned int w) { return __uint_as_float(w << 16); }
__device__ __forceinline__ float hi2f(unsigned int w) { return __uint_as_float(w & 0xFFFF0000u); }

// ---- fused: T row j = (ssp(g@f1+b1)@f2 + b2)*cut, packed bf16 pairs -> tabp ----
// tabp[j*64+l] = bf16(T[j][2l]) | bf16(T[j][2l+1])<<16 ; j = 0..TN (257 rows)
__global__ __launch_bounds__(128) void k_tablepack(
    const float* __restrict__ f1w, const float* __restrict__ f1b,
    const float* __restrict__ f2w, const float* __restrict__ f2b,
    unsigned int* __restrict__ tabp)
{
    int j = blockIdx.x;
    int f = threadIdx.x;
    float d = (float)j * (5.0f / (float)TN);

    constexpr float width = 5.0f / 24.0f;
    constexpr float coeff = -0.5f / (width * width);

    float z = f1b[f];
    #pragma unroll
    for (int c = 0; c < NG; ++c) {
        float t = d - (float)c * width;
        float g = __expf(coeff * t * t);
        z = fmaf(g, f1w[c * F + f], z);
    }
    __shared__ float sh[F];
    __shared__ float row[F];
    sh[f] = ssp(z);
    __syncthreads();

    float w = f2b[f];
    #pragma unroll 8
    for (int c = 0; c < F; ++c)
        w = fmaf(sh[c], f2w[c * F + f], w);

    float cut = 0.5f * (cosf(d * 0.62831853071795864769f) + 1.0f);
    cut = (d < 5.0f) ? cut : 0.0f;
    row[f] = w * cut;
    __syncthreads();
    if (f < 64)
        tabp[j * 64 + f] = f2bf(row[2 * f]) | (f2bf(row[2 * f + 1]) << 16);
}

// ---- pre-swizzle o1w/o2w into MFMA B-frag-major bf16 ----
__global__ __launch_bounds__(256) void k_prepw(
    const float* __restrict__ o1w, const float* __restrict__ o2w,
    unsigned short* __restrict__ o1frag, unsigned short* __restrict__ o2frag)
{
    int t = blockIdx.x * 256 + threadIdx.x;   // 0..32767
    if (t >= 32768) return;
    int e = t & 16383;
    int j = e & 7, l = (e >> 3) & 63, nt = (e >> 9) & 7, kt = e >> 12;
    int k = kt * 32 + ((l >> 4) << 3) + j;
    int col = nt * 16 + (l & 15);
    if (t < 16384) o1frag[e] = (unsigned short)f2bf(o1w[k * F + col]);
    else           o2frag[e] = (unsigned short)f2bf(o2w[k * F + col]);
}

// ---- yzp[z][l] = pack(yz[z][2l], yz[z][2l+1]), yz = embed @ in2f; row MAXZ = 0 ----
__global__ __launch_bounds__(128) void k_embedproj(
    const float* __restrict__ embed, const float* __restrict__ in2f_w,
    unsigned int* __restrict__ yzp)
{
    int z = blockIdx.x;          // 0..MAXZ
    int f = threadIdx.x;
    __shared__ float sx[F];
    __shared__ float row[F];
    if (z < MAXZ) {
        sx[f] = embed[z * F + f];
        __syncthreads();
        float acc = 0.f;
        #pragma unroll 8
        for (int c = 0; c < F; ++c)
            acc = fmaf(sx[c], in2f_w[c * F + f], acc);
        row[f] = acc;
    } else {
        row[f] = 0.f;
    }
    __syncthreads();
    if (f < 64)
        yzp[z * 64 + f] = f2bf(row[2 * f]) | (f2bf(row[2 * f + 1]) << 16);
}

// ---- per-pair params: (fr_bf16 << 16) | (j << 7) | z   (all-scalar decode) ----
__global__ __launch_bounds__(256) void k_params(
    const float* __restrict__ dR, const int* __restrict__ nbr,
    const int* __restrict__ Z, unsigned int* __restrict__ params, int N)
{
    int e = blockIdx.x * 256 + threadIdx.x;
    if (e >= N * KN) return;
    float d = dR[e];
    int   i = nbr[e];
    float u = d * ((float)TN / 5.0f);
    int   j = (int)u; j = (j > TN - 1) ? (TN - 1) : j;
    float fr = u - (float)j;
    unsigned int z = (i >= 0 && i < N) ? (unsigned int)Z[i] : (unsigned int)MAXZ;
    params[e] = (f2bf(fr) << 16) | ((unsigned int)j << 7) | z;
}

// ---- Core: table in LDS, scalar param decode, 2 atoms/wave, grid-stride ----
__global__ __launch_bounds__(512, 4) void k_pairagg(
    const unsigned int* __restrict__ params,
    const unsigned int* __restrict__ tabp,
    const unsigned int* __restrict__ yzp,
    unsigned int* __restrict__ aggb, int N)
{
    extern __shared__ unsigned int tabL[];    // 257*64 u32 = 65792 B
    int tid = threadIdx.x;
    for (int m = tid; m < (TN + 1) * 64; m += 512)
        tabL[m] = tabp[m];
    __syncthreads();

    int wid  = tid >> 6;
    int lane = tid & 63;
    int duos = (N + 1) >> 1;

    for (int d0 = blockIdx.x * 8 + wid; d0 < duos; d0 += 4096) {
        int nA = 2 * d0;
        int nB = nA + 1;
        bool vB = (nB < N);
        int baseA = __builtin_amdgcn_readfirstlane(nA) * KN;
        int baseB = __builtin_amdgcn_readfirstlane(vB ? nB : nA) * KN;

        float a0 = 0.f, a1 = 0.f, b0 = 0.f, b1 = 0.f;
        #pragma unroll 4
        for (int k = 0; k < KN; ++k) {
            unsigned int pA = params[baseA + k];
            unsigned int pB = params[baseB + k];

            float frA = __uint_as_float(pA & 0xFFFF0000u);   // scalar and
            float frB = __uint_as_float(pB & 0xFFFF0000u);
            unsigned int jbA = (pA & 0x7F80u) << 1;          // j*256 (byte off)
            unsigned int jbB = (pB & 0x7F80u) << 1;
            unsigned int zbA = (pA & 0x7Fu) << 8;            // z*256 (byte off)
            unsigned int zbB = (pB & 0x7Fu) << 8;

            const unsigned int* rA = (const unsigned int*)((const char*)tabL + jbA);
            const unsigned int* rB = (const unsigned int*)((const char*)tabL + jbB);
            unsigned int tA0 = rA[lane];
            unsigned int tA1 = rA[lane + 64];
            unsigned int tB0 = rB[lane];
            unsigned int tB1 = rB[lane + 64];
            unsigned int yA  = *(const unsigned int*)((const char*)yzp + zbA + (lane << 2));
            unsigned int yB  = *(const unsigned int*)((const char*)yzp + zbB + (lane << 2));

            float wA0 = fmaf(frA, lo2f(tA1) - lo2f(tA0), lo2f(tA0));
            float wA1 = fmaf(frA, hi2f(tA1) - hi2f(tA0), hi2f(tA0));
            a0 = fmaf(wA0, lo2f(yA), a0);
            a1 = fmaf(wA1, hi2f(yA), a1);

            float wB0 = fmaf(frB, lo2f(tB1) - lo2f(tB0), lo2f(tB0));
            float wB1 = fmaf(frB, hi2f(tB1) - hi2f(tB0), hi2f(tB0));
            b0 = fmaf(wB0, lo2f(yB), b0);
            b1 = fmaf(wB1, hi2f(yB), b1);
        }

        aggb[nA * 64 + lane] = f2bf(a0) | (f2bf(a1) << 16);
        if (vB) aggb[nB * 64 + lane] = f2bf(b0) | (f2bf(b1) << 16);
    }
}

// ---- Output network via MFMA: 32 atoms/block, 4 waves ----
__global__ __launch_bounds__(256) void k_outm(
    const unsigned int* __restrict__ aggb,
    const unsigned short* __restrict__ o1frag, const float* __restrict__ o1b,
    const unsigned short* __restrict__ o2frag, const float* __restrict__ o2b,
    const float* __restrict__ embed, const int* __restrict__ Z,
    float* __restrict__ out, int N)
{
    int a0  = blockIdx.x * 32;
    int tid = threadIdx.x;
    int w   = tid >> 6;
    int l   = tid & 63;
    int lr  = l & 15;
    int lg  = l >> 4;

    __shared__ int sZ[32];
    __shared__ __align__(16) unsigned short Us[32 * F];  // bf16 u, XOR-swizzled

    if (tid < 32) {
        int n = a0 + tid;
        sZ[tid] = (n < N) ? Z[n] : 0;
    }

    const unsigned short* aggh = (const unsigned short*)aggb;

    f32x4 zero = {0.f, 0.f, 0.f, 0.f};
    f32x4 c1[2][2];
    #pragma unroll
    for (int mt = 0; mt < 2; ++mt) { c1[mt][0] = zero; c1[mt][1] = zero; }

    #pragma unroll
    for (int kt = 0; kt < 4; ++kt) {
        bf16x8 b0 = *reinterpret_cast<const bf16x8*>(o1frag + (((kt * 8 + 2 * w + 0) * 64 + l) << 3));
        bf16x8 b1 = *reinterpret_cast<const bf16x8*>(o1frag + (((kt * 8 + 2 * w + 1) * 64 + l) << 3));
        #pragma unroll
        for (int mt = 0; mt < 2; ++mt) {
            int row = a0 + mt * 16 + lr;
            row = (row < N) ? row : N - 1;
            bf16x8 a = *reinterpret_cast<const bf16x8*>(aggh + row * F + kt * 32 + lg * 8);
            c1[mt][0] = __builtin_amdgcn_mfma_f32_16x16x32_bf16(a, b0, c1[mt][0], 0, 0, 0);
            c1[mt][1] = __builtin_amdgcn_mfma_f32_16x16x32_bf16(a, b1, c1[mt][1], 0, 0, 0);
        }
    }

    #pragma unroll
    for (int ntl = 0; ntl < 2; ++ntl) {
        int fcol = (2 * w + ntl) * 16 + lr;
        float bv = o1b[fcol];
        #pragma unroll
        for (int mt = 0; mt < 2; ++mt) {
            #pragma unroll
            for (int jr = 0; jr < 4; ++jr) {
                int r = mt * 16 + lg * 4 + jr;
                float u = ssp(c1[mt][ntl][jr] + bv);
                Us[r * F + (fcol ^ ((r & 15) << 3))] = (unsigned short)f2bf(u);
            }
        }
    }
    __syncthreads();

    f32x4 c2[2][2];
    #pragma unroll
    for (int mt = 0; mt < 2; ++mt) { c2[mt][0] = zero; c2[mt][1] = zero; }

    #pragma unroll
    for (int kt = 0; kt < 4; ++kt) {
        bf16x8 b0 = *reinterpret_cast<const bf16x8*>(o2frag + (((kt * 8 + 2 * w + 0) * 64 + l) << 3));
        bf16x8 b1 = *reinterpret_cast<const bf16x8*>(o2frag + (((kt * 8 + 2 * w + 1) * 64 + l) << 3));
        #pragma unroll
        for (int mt = 0; mt < 2; ++mt) {
            int r = mt * 16 + lr;
            bf16x8 a = *reinterpret_cast<const bf16x8*>(&Us[r * F + ((kt * 32 + lg * 8) ^ ((r & 15) << 3))]);
            c2[mt][0] = __builtin_amdgcn_mfma_f32_16x16x32_bf16(a, b0, c2[mt][0], 0, 0, 0);
            c2[mt][1] = __builtin_amdgcn_mfma_f32_16x16x32_bf16(a, b1, c2[mt][1], 0, 0, 0);
        }
    }

    #pragma unroll
    for (int ntl = 0; ntl < 2; ++ntl) {
        int fcol = (2 * w + ntl) * 16 + lr;
        float bv = o2b[fcol];
        #pragma unroll
        for (int mt = 0; mt < 2; ++mt) {
            #pragma unroll
            for (int jr = 0; jr < 4; ++jr) {
                int r = mt * 16 + lg * 4 + jr;
                int n = a0 + r;
                if (n < N) {
                    float x = embed[sZ[r] * F + fcol];
                    out[n * F + fcol] = x + c2[mt][ntl][jr] + bv;
                }
            }
        }
    }
}

extern "C" void kernel_launch(void* const* d_in, const int* in_sizes, int n_in,
                              void* d_out, int out_size, void* d_ws, size_t ws_size,
                              hipStream_t stream) {
    const float* dR    = (const float*)d_in[0];
    const int*   Z     = (const int*)  d_in[1];
    const int*   nbr   = (const int*)  d_in[2];
    const float* embed = (const float*)d_in[3];
    const float* in2f  = (const float*)d_in[4];
    const float* f1w   = (const float*)d_in[5];
    const float* f1b   = (const float*)d_in[6];
    const float* f2w   = (const float*)d_in[7];
    const float* f2b   = (const float*)d_in[8];
    const float* o1w   = (const float*)d_in[9];
    const float* o1b   = (const float*)d_in[10];
    const float* o2w   = (const float*)d_in[11];
    const float* o2b   = (const float*)d_in[12];

    int N = in_sizes[1];

    // ws layout (all 16B-aligned); total ~9.1 MB
    char* wp = (char*)d_ws;
    unsigned int*   params = (unsigned int*)wp;   wp += (size_t)N * KN * 4;        // 3.84 MB
    unsigned int*   tabp   = (unsigned int*)wp;   wp += (size_t)(TN + 1) * 64 * 4; // 65.8 KB
    unsigned int*   yzp    = (unsigned int*)wp;   wp += (size_t)(MAXZ + 1) * 64 * 4; // 25.9 KB
    unsigned short* o1f    = (unsigned short*)wp; wp += 16384 * 2;                 // 32 KB
    unsigned short* o2f    = (unsigned short*)wp; wp += 16384 * 2;                 // 32 KB
    unsigned int*   aggb   = (unsigned int*)wp;                                    // 5.12 MB

    (void)hipFuncSetAttribute((const void*)k_pairagg,
                              hipFuncAttributeMaxDynamicSharedMemorySize,
                              (TN + 1) * 64 * 4);

    k_tablepack<<<TN + 1, 128, 0, stream>>>(f1w, f1b, f2w, f2b, tabp);
    k_prepw<<<128, 256, 0, stream>>>(o1w, o2w, o1f, o2f);
    k_embedproj<<<MAXZ + 1, 128, 0, stream>>>(embed, in2f, yzp);
    k_params<<<(N * KN + 255) / 256, 256, 0, stream>>>(dR, nbr, Z, params, N);
    k_pairagg<<<512, 512, (TN + 1) * 64 * 4, stream>>>(params, tabp, yzp, aggb, N);
    k_outm<<<(N + 31) / 32, 256, 0, stream>>>(aggb, o1f, o1b, o2f, o2b,
                                              embed, Z, (float*)d_out, N);
}

// Round 8
// 45.330 us; speedup vs baseline: 23.2231x; 1.3619x over previous
//
#include <hip/hip_runtime.h>
#include <math.h>

constexpr int F    = 128;
constexpr int KN   = 48;
constexpr int NG   = 25;
constexpr int TN   = 256;         // table intervals; 257 nodes, h = 5/256
constexpr int MAXZ = 100;

typedef short bf16x8 __attribute__((ext_vector_type(8)));
typedef float f32x4  __attribute__((ext_vector_type(4)));

__device__ __forceinline__ float ssp(float x) {
    // softplus(x) - ln2 = max(x,0) + log(0.5*exp(-|x|) + 0.5)
    return fmaxf(x, 0.0f) + __logf(fmaf(0.5f, __expf(-fabsf(x)), 0.5f));
}

__device__ __forceinline__ unsigned int f2bf(float x) {
    unsigned int u = __float_as_uint(x);
    return (u + 0x7FFFu + ((u >> 16) & 1u)) >> 16;   // RNE bf16 (low 16 bits)
}
__device__ __forceinline__ float lo2f(unsigned int w) { return __uint_as_float(w << 16); }
__device__ __forceinline__ float hi2f(unsigned int w) { return __uint_as_float(w & 0xFFFF0000u); }

// ================= fused prep: params | tablepack | prepw | embedproj ========
// grid = nparam_blk + (TN+1) + 128 + (MAXZ+1), 256 threads
__global__ __launch_bounds__(256) void k_prep(
    const float* __restrict__ dR, const int* __restrict__ nbr,
    const int* __restrict__ Z,
    const float* __restrict__ f1w, const float* __restrict__ f1b,
    const float* __restrict__ f2w, const float* __restrict__ f2b,
    const float* __restrict__ o1w, const float* __restrict__ o2w,
    const float* __restrict__ embed, const float* __restrict__ in2f,
    unsigned int* __restrict__ params, unsigned int* __restrict__ tabp,
    unsigned int* __restrict__ yzp,
    unsigned short* __restrict__ o1f, unsigned short* __restrict__ o2f, int N)
{
    __shared__ float s0[F];
    __shared__ float s1[F];
    int bid = blockIdx.x;
    int tid = threadIdx.x;
    int nparam_blk = (N * KN + 255) >> 8;

    if (bid < nparam_blk) {
        // ---- params: (fr_bf16 << 16) | (j << 7) | z ----
        int e = bid * 256 + tid;
        if (e < N * KN) {
            float d = dR[e];
            int   i = nbr[e];
            float u = d * ((float)TN / 5.0f);
            int   j = (int)u; j = (j > TN - 1) ? (TN - 1) : j;
            float fr = u - (float)j;
            unsigned int z = (i >= 0 && i < N) ? (unsigned int)Z[i] : (unsigned int)MAXZ;
            params[e] = (f2bf(fr) << 16) | ((unsigned int)j << 7) | z;
        }
        return;
    }
    bid -= nparam_blk;

    if (bid < TN + 1) {
        // ---- table row j, packed bf16 pairs ----
        int j = bid, f = tid;
        float d = (float)j * (5.0f / (float)TN);
        constexpr float width = 5.0f / 24.0f;
        constexpr float coeff = -0.5f / (width * width);
        if (f < F) {
            float z = f1b[f];
            #pragma unroll
            for (int c = 0; c < NG; ++c) {
                float t = d - (float)c * width;
                z = fmaf(__expf(coeff * t * t), f1w[c * F + f], z);
            }
            s0[f] = ssp(z);
        }
        __syncthreads();
        if (f < F) {
            float w = f2b[f];
            #pragma unroll 8
            for (int c = 0; c < F; ++c)
                w = fmaf(s0[c], f2w[c * F + f], w);
            float cut = 0.5f * (cosf(d * 0.62831853071795864769f) + 1.0f);
            cut = (d < 5.0f) ? cut : 0.0f;
            s1[f] = w * cut;
        }
        __syncthreads();
        if (f < 64)
            tabp[j * 64 + f] = f2bf(s1[2 * f]) | (f2bf(s1[2 * f + 1]) << 16);
        return;
    }
    bid -= TN + 1;

    if (bid < 128) {
        // ---- o1w/o2w -> MFMA B-frag-major bf16 ----
        int t = bid * 256 + tid;            // 0..32767
        int e = t & 16383;
        int j = e & 7, l = (e >> 3) & 63, nt = (e >> 9) & 7, kt = e >> 12;
        int k = kt * 32 + ((l >> 4) << 3) + j;
        int col = nt * 16 + (l & 15);
        if (t < 16384) o1f[e] = (unsigned short)f2bf(o1w[k * F + col]);
        else           o2f[e] = (unsigned short)f2bf(o2w[k * F + col]);
        return;
    }
    bid -= 128;

    {
        // ---- yzp[z] = packed bf16 of embed[z] @ in2f; row MAXZ = 0 ----
        int z = bid, f = tid;
        if (z < MAXZ) {
            if (f < F) s0[f] = embed[z * F + f];
            __syncthreads();
            if (f < F) {
                float acc = 0.f;
                #pragma unroll 8
                for (int c = 0; c < F; ++c)
                    acc = fmaf(s0[c], in2f[c * F + f], acc);
                s1[f] = acc;
            }
        } else {
            if (f < F) s1[f] = 0.f;
            __syncthreads();
        }
        __syncthreads();
        if (f < 64)
            yzp[z * 64 + f] = f2bf(s1[2 * f]) | (f2bf(s1[2 * f + 1]) << 16);
    }
}

// ================= fused main: pairagg + output network ======================
// 512 threads (8 waves), persistent grid. Per 16-atom group:
//   phase1: wave w computes agg for atoms 2w, 2w+1 -> swizzled bf16 aggL
//   phase2: wave w = col-tile w of out-net (MFMA1 -> ssp -> MFMA2 -> +residual)
// LDS: tabL 65792 B | aggL 4096 B | Us 4096 B  = 74 KB -> 2 blocks/CU
__global__ __launch_bounds__(512, 4) void k_main(
    const unsigned int* __restrict__ params,
    const unsigned int* __restrict__ tabp,
    const unsigned int* __restrict__ yzp,
    const unsigned short* __restrict__ o1f, const float* __restrict__ o1b,
    const unsigned short* __restrict__ o2f, const float* __restrict__ o2b,
    const float* __restrict__ embed, const int* __restrict__ Z,
    float* __restrict__ out, int N, int ngroups)
{
    extern __shared__ unsigned int smem[];
    unsigned int*   tabL = smem;                                   // 16448 u32
    unsigned int*   aggL = smem + 16448;                           // 1024 u32
    unsigned short* Us   = (unsigned short*)(smem + 16448 + 1024); // 2048 u16

    int tid  = threadIdx.x;
    int wid  = tid >> 6;
    int lane = tid & 63;
    int lr   = lane & 15;
    int lg   = lane >> 4;

    for (int m = tid; m < (TN + 1) * 64; m += 512)
        tabL[m] = tabp[m];
    __syncthreads();

    for (int g = blockIdx.x; g < ngroups; g += gridDim.x) {
        int n0 = g * 16;

        // ---------- phase 1: pair aggregation, 2 atoms per wave ----------
        int aA = wid * 2, aB = aA + 1;
        int nA = n0 + aA, nB = n0 + aB;
        float a0 = 0.f, a1 = 0.f, b0 = 0.f, b1 = 0.f;
        if (nA < N) {
            int mB = (nB < N) ? nB : nA;
            int baseA = __builtin_amdgcn_readfirstlane(nA) * KN;
            int baseB = __builtin_amdgcn_readfirstlane(mB) * KN;
            #pragma unroll 4
            for (int k = 0; k < KN; ++k) {
                unsigned int pA = params[baseA + k];
                unsigned int pB = params[baseB + k];

                float frA = __uint_as_float(pA & 0xFFFF0000u);
                float frB = __uint_as_float(pB & 0xFFFF0000u);
                unsigned int jbA = (pA & 0x7F80u) << 1;   // j*256 bytes
                unsigned int jbB = (pB & 0x7F80u) << 1;
                unsigned int zbA = (pA & 0x7Fu) << 8;     // z*256 bytes
                unsigned int zbB = (pB & 0x7Fu) << 8;

                const unsigned int* rA = (const unsigned int*)((const char*)tabL + jbA);
                const unsigned int* rB = (const unsigned int*)((const char*)tabL + jbB);
                unsigned int tA0 = rA[lane];
                unsigned int tA1 = rA[lane + 64];
                unsigned int tB0 = rB[lane];
                unsigned int tB1 = rB[lane + 64];
                unsigned int yA  = *(const unsigned int*)((const char*)yzp + zbA + (lane << 2));
                unsigned int yB  = *(const unsigned int*)((const char*)yzp + zbB + (lane << 2));

                float wA0 = fmaf(frA, lo2f(tA1) - lo2f(tA0), lo2f(tA0));
                float wA1 = fmaf(frA, hi2f(tA1) - hi2f(tA0), hi2f(tA0));
                a0 = fmaf(wA0, lo2f(yA), a0);
                a1 = fmaf(wA1, hi2f(yA), a1);

                float wB0 = fmaf(frB, lo2f(tB1) - lo2f(tB0), lo2f(tB0));
                float wB1 = fmaf(frB, hi2f(tB1) - hi2f(tB0), hi2f(tB0));
                b0 = fmaf(wB0, lo2f(yB), b0);
                b1 = fmaf(wB1, hi2f(yB), b1);
            }
        }
        // swizzled store: word idx = a*64 + (lane ^ (a<<2))
        aggL[aA * 64 + (lane ^ (aA << 2))] = f2bf(a0) | (f2bf(a1) << 16);
        aggL[aB * 64 + (lane ^ (aB << 2))] = f2bf(b0) | (f2bf(b1) << 16);
        __syncthreads();                       // bar1: aggL ready

        // ---------- phase 2: output network, col-tile = wid ----------
        f32x4 c1 = {0.f, 0.f, 0.f, 0.f};
        #pragma unroll
        for (int kt = 0; kt < 4; ++kt) {
            bf16x8 b = *reinterpret_cast<const bf16x8*>(o1f + (((kt * 8 + wid) * 64 + lane) << 3));
            const char* ap = (const char*)aggL + lr * 256 + ((kt * 64 + lg * 16) ^ (lr << 4));
            bf16x8 a = *reinterpret_cast<const bf16x8*>(ap);
            c1 = __builtin_amdgcn_mfma_f32_16x16x32_bf16(a, b, c1, 0, 0, 0);
        }
        int fcol = wid * 16 + lr;
        float bv1 = o1b[fcol];
        #pragma unroll
        for (int jr = 0; jr < 4; ++jr) {
            int r = lg * 4 + jr;
            float u = ssp(c1[jr] + bv1);
            Us[r * F + (fcol ^ (r << 3))] = (unsigned short)f2bf(u);
        }
        __syncthreads();                       // bar2: Us ready

        f32x4 c2 = {0.f, 0.f, 0.f, 0.f};
        #pragma unroll
        for (int kt = 0; kt < 4; ++kt) {
            bf16x8 b = *reinterpret_cast<const bf16x8*>(o2f + (((kt * 8 + wid) * 64 + lane) << 3));
            bf16x8 a = *reinterpret_cast<const bf16x8*>(&Us[lr * F + ((kt * 32 + lg * 8) ^ (lr << 3))]);
            c2 = __builtin_amdgcn_mfma_f32_16x16x32_bf16(a, b, c2, 0, 0, 0);
        }
        float bv2 = o2b[fcol];
        #pragma unroll
        for (int jr = 0; jr < 4; ++jr) {
            int r = lg * 4 + jr;
            int n = n0 + r;
            if (n < N) {
                float x = embed[Z[n] * F + fcol];
                out[n * F + fcol] = x + c2[jr] + bv2;
            }
        }
        // next group's aggL/Us writes are fenced by this group's bar2 + next bar1
    }
}

extern "C" void kernel_launch(void* const* d_in, const int* in_sizes, int n_in,
                              void* d_out, int out_size, void* d_ws, size_t ws_size,
                              hipStream_t stream) {
    const float* dR    = (const float*)d_in[0];
    const int*   Z     = (const int*)  d_in[1];
    const int*   nbr   = (const int*)  d_in[2];
    const float* embed = (const float*)d_in[3];
    const float* in2f  = (const float*)d_in[4];
    const float* f1w   = (const float*)d_in[5];
    const float* f1b   = (const float*)d_in[6];
    const float* f2w   = (const float*)d_in[7];
    const float* f2b   = (const float*)d_in[8];
    const float* o1w   = (const float*)d_in[9];
    const float* o1b   = (const float*)d_in[10];
    const float* o2w   = (const float*)d_in[11];
    const float* o2b   = (const float*)d_in[12];

    int N = in_sizes[1];

    // ws layout (16B-aligned), total ~4.0 MB
    char* wp = (char*)d_ws;
    unsigned int*   params = (unsigned int*)wp;   wp += (size_t)N * KN * 4;          // 3.84 MB
    unsigned int*   tabp   = (unsigned int*)wp;   wp += (size_t)(TN + 1) * 64 * 4;   // 65.8 KB
    unsigned int*   yzp    = (unsigned int*)wp;   wp += (size_t)(MAXZ + 1) * 64 * 4; // 25.9 KB
    unsigned short* o1f    = (unsigned short*)wp; wp += 16384 * 2;                   // 32 KB
    unsigned short* o2f    = (unsigned short*)wp;                                    // 32 KB

    int nparam_blk = (N * KN + 255) / 256;
    int grid_prep  = nparam_blk + (TN + 1) + 128 + (MAXZ + 1);

    int ngroups   = (N + 15) / 16;
    int grid_main = (ngroups < 512) ? ngroups : 512;
    int lds_main  = (TN + 1) * 64 * 4 + 4096 + 4096;   // 74 KB

    (void)hipFuncSetAttribute((const void*)k_main,
                              hipFuncAttributeMaxDynamicSharedMemorySize, lds_main);

    k_prep<<<grid_prep, 256, 0, stream>>>(dR, nbr, Z, f1w, f1b, f2w, f2b,
                                          o1w, o2w, embed, in2f,
                                          params, tabp, yzp, o1f, o2f, N);
    k_main<<<grid_main, 512, lds_main, stream>>>(params, tabp, yzp,
                                                 o1f, o1b, o2f, o2b,
                                                 embed, Z, (float*)d_out,
                                                 N, ngroups);
}

// Round 9
// 41.824 us; speedup vs baseline: 25.1699x; 1.0838x over previous
//
#include <hip/hip_runtime.h>
#include <hip/hip_fp16.h>
#include <math.h>

constexpr int F    = 128;
constexpr int KN   = 48;
constexpr int NG   = 25;
constexpr int TN   = 256;         // table intervals; 257 nodes, h = 5/256
constexpr int MAXZ = 100;

typedef _Float16 f16x8 __attribute__((ext_vector_type(8)));
typedef float    f32x4 __attribute__((ext_vector_type(4)));

__device__ __forceinline__ float ssp(float x) {
    // softplus(x) - ln2 = max(x,0) + log(0.5*exp(-|x|) + 0.5)
    return fmaxf(x, 0.0f) + __logf(fmaf(0.5f, __expf(-fabsf(x)), 0.5f));
}

__device__ __forceinline__ unsigned short f2h(float x) {
    return __half_as_ushort(__float2half_rn(x));
}
__device__ __forceinline__ __half2 u2h2(unsigned int u) {
    union { unsigned int u; __half2 h; } c; c.u = u; return c.h;
}

// ================= fused prep: params | tablepack | prepw | embedproj ========
__global__ __launch_bounds__(256) void k_prep(
    const float* __restrict__ dR, const int* __restrict__ nbr,
    const int* __restrict__ Z,
    const float* __restrict__ f1w, const float* __restrict__ f1b,
    const float* __restrict__ f2w, const float* __restrict__ f2b,
    const float* __restrict__ o1w, const float* __restrict__ o2w,
    const float* __restrict__ embed, const float* __restrict__ in2f,
    unsigned int* __restrict__ params, unsigned int* __restrict__ tabp,
    unsigned int* __restrict__ yzp,
    unsigned short* __restrict__ o1f, unsigned short* __restrict__ o2f, int N)
{
    __shared__ float s0[F];
    __shared__ float s1[F];
    int bid = blockIdx.x;
    int tid = threadIdx.x;
    int nparam_blk = (N * KN + 255) >> 8;

    if (bid < nparam_blk) {
        // ---- params: (fr_f16 << 16) | (j << 7) | z ----
        int e = bid * 256 + tid;
        if (e < N * KN) {
            float d = dR[e];
            int   i = nbr[e];
            float u = d * ((float)TN / 5.0f);
            int   j = (int)u; j = (j > TN - 1) ? (TN - 1) : j;
            float fr = u - (float)j;
            unsigned int z = (i >= 0 && i < N) ? (unsigned int)Z[i] : (unsigned int)MAXZ;
            params[e] = ((unsigned int)f2h(fr) << 16) | ((unsigned int)j << 7) | z;
        }
        return;
    }
    bid -= nparam_blk;

    if (bid < TN + 1) {
        // ---- table row j, packed f16 pairs ----
        int j = bid, f = tid;
        float d = (float)j * (5.0f / (float)TN);
        constexpr float width = 5.0f / 24.0f;
        constexpr float coeff = -0.5f / (width * width);
        if (f < F) {
            float z = f1b[f];
            #pragma unroll
            for (int c = 0; c < NG; ++c) {
                float t = d - (float)c * width;
                z = fmaf(__expf(coeff * t * t), f1w[c * F + f], z);
            }
            s0[f] = ssp(z);
        }
        __syncthreads();
        if (f < F) {
            float w = f2b[f];
            #pragma unroll 8
            for (int c = 0; c < F; ++c)
                w = fmaf(s0[c], f2w[c * F + f], w);
            float cut = 0.5f * (cosf(d * 0.62831853071795864769f) + 1.0f);
            cut = (d < 5.0f) ? cut : 0.0f;
            s1[f] = w * cut;
        }
        __syncthreads();
        if (f < 64)
            tabp[j * 64 + f] = (unsigned int)f2h(s1[2 * f]) | ((unsigned int)f2h(s1[2 * f + 1]) << 16);
        return;
    }
    bid -= TN + 1;

    if (bid < 128) {
        // ---- o1w/o2w -> MFMA B-frag-major f16 ----
        int t = bid * 256 + tid;            // 0..32767
        int e = t & 16383;
        int j = e & 7, l = (e >> 3) & 63, nt = (e >> 9) & 7, kt = e >> 12;
        int k = kt * 32 + ((l >> 4) << 3) + j;
        int col = nt * 16 + (l & 15);
        if (t < 16384) o1f[e] = f2h(o1w[k * F + col]);
        else           o2f[e] = f2h(o2w[k * F + col]);
        return;
    }
    bid -= 128;

    {
        // ---- yzp[z] = packed f16 of embed[z] @ in2f; row MAXZ = 0 ----
        int z = bid, f = tid;
        if (z < MAXZ) {
            if (f < F) s0[f] = embed[z * F + f];
            __syncthreads();
            if (f < F) {
                float acc = 0.f;
                #pragma unroll 8
                for (int c = 0; c < F; ++c)
                    acc = fmaf(s0[c], in2f[c * F + f], acc);
                s1[f] = acc;
            }
        } else {
            if (f < F) s1[f] = 0.f;
            __syncthreads();
        }
        __syncthreads();
        if (f < 64)
            yzp[z * 64 + f] = (unsigned int)f2h(s1[2 * f]) | ((unsigned int)f2h(s1[2 * f + 1]) << 16);
    }
}

// ================= fused main: pairagg (packed f16) + output net (f16 MFMA) ==
// 512 threads (8 waves), persistent. Per 16-atom group:
//   phase1: wave w -> atoms 2w,2w+1; packed-f16 lerp+weight+accum (4x12 chunks)
//   phase2: wave w = col-tile w of out-net (MFMA1 -> ssp -> MFMA2 -> +residual)
// LDS: tabL 65792 B | aggL 4096 B | Us 4096 B = 74 KB -> 2 blocks/CU
__global__ __launch_bounds__(512, 4) void k_main(
    const unsigned int* __restrict__ params,
    const unsigned int* __restrict__ tabp,
    const unsigned int* __restrict__ yzp,
    const unsigned short* __restrict__ o1f, const float* __restrict__ o1b,
    const unsigned short* __restrict__ o2f, const float* __restrict__ o2b,
    const float* __restrict__ embed, const int* __restrict__ Z,
    float* __restrict__ out, int N, int ngroups)
{
    extern __shared__ unsigned int smem[];
    unsigned int*   tabL = smem;                                   // 16448 u32
    unsigned int*   aggL = smem + 16448;                           // 1024 u32
    unsigned short* Us   = (unsigned short*)(smem + 16448 + 1024); // 2048 u16

    int tid  = threadIdx.x;
    int wid  = tid >> 6;
    int lane = tid & 63;
    int lr   = lane & 15;
    int lg   = lane >> 4;

    for (int m = tid; m < (TN + 1) * 64; m += 512)
        tabL[m] = tabp[m];
    __syncthreads();

    for (int g = blockIdx.x; g < ngroups; g += gridDim.x) {
        int n0 = g * 16;

        // ---------- phase 1: pair aggregation, 2 atoms per wave ----------
        int aA = wid * 2, aB = aA + 1;
        int nA = n0 + aA, nB = n0 + aB;
        float a0 = 0.f, a1 = 0.f, b0 = 0.f, b1 = 0.f;
        if (nA < N) {
            int mB = (nB < N) ? nB : nA;
            int baseA = __builtin_amdgcn_readfirstlane(nA) * KN;
            int baseB = __builtin_amdgcn_readfirstlane(mB) * KN;
            #pragma unroll
            for (int c = 0; c < 4; ++c) {
                __half2 pacA = u2h2(0u);
                __half2 pacB = u2h2(0u);
                #pragma unroll 4
                for (int k2 = 0; k2 < 12; ++k2) {
                    int k = c * 12 + k2;
                    unsigned int pA = params[baseA + k];
                    unsigned int pB = params[baseB + k];

                    __half2 frA = u2h2((pA & 0xFFFF0000u) | (pA >> 16));
                    __half2 frB = u2h2((pB & 0xFFFF0000u) | (pB >> 16));
                    unsigned int jbA = (pA & 0x7F80u) << 1;   // j*256 bytes
                    unsigned int jbB = (pB & 0x7F80u) << 1;
                    unsigned int zbA = (pA & 0x7Fu) << 8;     // z*256 bytes
                    unsigned int zbB = (pB & 0x7Fu) << 8;

                    const unsigned int* rA = (const unsigned int*)((const char*)tabL + jbA);
                    const unsigned int* rB = (const unsigned int*)((const char*)tabL + jbB);
                    __half2 tA0 = u2h2(rA[lane]);
                    __half2 tA1 = u2h2(rA[lane + 64]);
                    __half2 tB0 = u2h2(rB[lane]);
                    __half2 tB1 = u2h2(rB[lane + 64]);
                    __half2 yA  = u2h2(*(const unsigned int*)((const char*)yzp + zbA + (lane << 2)));
                    __half2 yB  = u2h2(*(const unsigned int*)((const char*)yzp + zbB + (lane << 2)));

                    __half2 wA = __hfma2(frA, __hsub2(tA1, tA0), tA0);
                    __half2 wB = __hfma2(frB, __hsub2(tB1, tB0), tB0);
                    pacA = __hfma2(wA, yA, pacA);
                    pacB = __hfma2(wB, yB, pacB);
                }
                float2 fa = __half22float2(pacA); a0 += fa.x; a1 += fa.y;
                float2 fb = __half22float2(pacB); b0 += fb.x; b1 += fb.y;
            }
        }
        // swizzled store: word idx = a*64 + (lane ^ (a<<2))
        aggL[aA * 64 + (lane ^ (aA << 2))] = (unsigned int)f2h(a0) | ((unsigned int)f2h(a1) << 16);
        aggL[aB * 64 + (lane ^ (aB << 2))] = (unsigned int)f2h(b0) | ((unsigned int)f2h(b1) << 16);
        __syncthreads();                       // bar1: aggL ready

        // ---------- phase 2: output network (f16 MFMA), col-tile = wid ----------
        f32x4 c1 = {0.f, 0.f, 0.f, 0.f};
        #pragma unroll
        for (int kt = 0; kt < 4; ++kt) {
            f16x8 b = *reinterpret_cast<const f16x8*>(o1f + (((kt * 8 + wid) * 64 + lane) << 3));
            const char* ap = (const char*)aggL + lr * 256 + ((kt * 64 + lg * 16) ^ (lr << 4));
            f16x8 a = *reinterpret_cast<const f16x8*>(ap);
            c1 = __builtin_amdgcn_mfma_f32_16x16x32_f16(a, b, c1, 0, 0, 0);
        }
        int fcol = wid * 16 + lr;
        float bv1 = o1b[fcol];
        #pragma unroll
        for (int jr = 0; jr < 4; ++jr) {
            int r = lg * 4 + jr;
            float u = ssp(c1[jr] + bv1);
            Us[r * F + (fcol ^ (r << 3))] = f2h(u);
        }
        __syncthreads();                       // bar2: Us ready

        f32x4 c2 = {0.f, 0.f, 0.f, 0.f};
        #pragma unroll
        for (int kt = 0; kt < 4; ++kt) {
            f16x8 b = *reinterpret_cast<const f16x8*>(o2f + (((kt * 8 + wid) * 64 + lane) << 3));
            f16x8 a = *reinterpret_cast<const f16x8*>(&Us[lr * F + ((kt * 32 + lg * 8) ^ (lr << 3))]);
            c2 = __builtin_amdgcn_mfma_f32_16x16x32_f16(a, b, c2, 0, 0, 0);
        }
        float bv2 = o2b[fcol];
        #pragma unroll
        for (int jr = 0; jr < 4; ++jr) {
            int r = lg * 4 + jr;
            int n = n0 + r;
            if (n < N) {
                float x = embed[Z[n] * F + fcol];
                out[n * F + fcol] = x + c2[jr] + bv2;
            }
        }
    }
}

extern "C" void kernel_launch(void* const* d_in, const int* in_sizes, int n_in,
                              void* d_out, int out_size, void* d_ws, size_t ws_size,
                              hipStream_t stream) {
    const float* dR    = (const float*)d_in[0];
    const int*   Z     = (const int*)  d_in[1];
    const int*   nbr   = (const int*)  d_in[2];
    const float* embed = (const float*)d_in[3];
    const float* in2f  = (const float*)d_in[4];
    const float* f1w   = (const float*)d_in[5];
    const float* f1b   = (const float*)d_in[6];
    const float* f2w   = (const float*)d_in[7];
    const float* f2b   = (const float*)d_in[8];
    const float* o1w   = (const float*)d_in[9];
    const float* o1b   = (const float*)d_in[10];
    const float* o2w   = (const float*)d_in[11];
    const float* o2b   = (const float*)d_in[12];

    int N = in_sizes[1];

    // ws layout (16B-aligned), total ~4.0 MB
    char* wp = (char*)d_ws;
    unsigned int*   params = (unsigned int*)wp;   wp += (size_t)N * KN * 4;          // 3.84 MB
    unsigned int*   tabp   = (unsigned int*)wp;   wp += (size_t)(TN + 1) * 64 * 4;   // 65.8 KB
    unsigned int*   yzp    = (unsigned int*)wp;   wp += (size_t)(MAXZ + 1) * 64 * 4; // 25.9 KB
    unsigned short* o1f    = (unsigned short*)wp; wp += 16384 * 2;                   // 32 KB
    unsigned short* o2f    = (unsigned short*)wp;                                    // 32 KB

    int nparam_blk = (N * KN + 255) / 256;
    int grid_prep  = nparam_blk + (TN + 1) + 128 + (MAXZ + 1);

    int ngroups   = (N + 15) / 16;
    int grid_main = (ngroups < 512) ? ngroups : 512;
    int lds_main  = (TN + 1) * 64 * 4 + 4096 + 4096;   // 74 KB

    (void)hipFuncSetAttribute((const void*)k_main,
                              hipFuncAttributeMaxDynamicSharedMemorySize, lds_main);

    k_prep<<<grid_prep, 256, 0, stream>>>(dR, nbr, Z, f1w, f1b, f2w, f2b,
                                          o1w, o2w, embed, in2f,
                                          params, tabp, yzp, o1f, o2f, N);
    k_main<<<grid_main, 512, lds_main, stream>>>(params, tabp, yzp,
                                                 o1f, o1b, o2f, o2b,
                                                 embed, Z, (float*)d_out,
                                                 N, ngroups);
}

// Round 10
// 37.119 us; speedup vs baseline: 28.3600x; 1.1267x over previous
//
#include <hip/hip_runtime.h>
#include <hip/hip_fp16.h>
#include <math.h>

constexpr int F    = 128;
constexpr int KN   = 48;
constexpr int NG   = 25;
constexpr int TN   = 176;         // table intervals; 177 nodes, h = 5/176
constexpr int MAXZ = 100;

typedef _Float16 f16x8 __attribute__((ext_vector_type(8)));
typedef float    f32x4 __attribute__((ext_vector_type(4)));

__device__ __forceinline__ float ssp(float x) {
    // softplus(x) - ln2 = max(x,0) + log(0.5*exp(-|x|) + 0.5)
    return fmaxf(x, 0.0f) + __logf(fmaf(0.5f, __expf(-fabsf(x)), 0.5f));
}

__device__ __forceinline__ unsigned short f2h(float x) {
    return __half_as_ushort(__float2half_rn(x));
}
__device__ __forceinline__ __half2 u2h2(unsigned int u) {
    union { unsigned int u; __half2 h; } c; c.u = u; return c.h;
}

// ============ prep: table rows | o-weight frags | embed projection ===========
// grid = (TN+1) + 128 + (MAXZ+1)
__global__ __launch_bounds__(256) void k_prep(
    const float* __restrict__ f1w, const float* __restrict__ f1b,
    const float* __restrict__ f2w, const float* __restrict__ f2b,
    const float* __restrict__ o1w, const float* __restrict__ o2w,
    const float* __restrict__ embed, const float* __restrict__ in2f,
    unsigned int* __restrict__ tabp, unsigned int* __restrict__ yzp,
    unsigned short* __restrict__ o1f, unsigned short* __restrict__ o2f, int N)
{
    __shared__ float s0[F];
    __shared__ float s1[F];
    int bid = blockIdx.x;
    int tid = threadIdx.x;

    if (bid < TN + 1) {
        // ---- table row j, packed f16 pairs ----
        int j = bid, f = tid;
        float d = (float)j * (5.0f / (float)TN);
        constexpr float width = 5.0f / 24.0f;
        constexpr float coeff = -0.5f / (width * width);
        if (f < F) {
            float z = f1b[f];
            #pragma unroll
            for (int c = 0; c < NG; ++c) {
                float t = d - (float)c * width;
                z = fmaf(__expf(coeff * t * t), f1w[c * F + f], z);
            }
            s0[f] = ssp(z);
        }
        __syncthreads();
        if (f < F) {
            float w = f2b[f];
            #pragma unroll 8
            for (int c = 0; c < F; ++c)
                w = fmaf(s0[c], f2w[c * F + f], w);
            float cut = 0.5f * (cosf(d * 0.62831853071795864769f) + 1.0f);
            cut = (d < 5.0f) ? cut : 0.0f;
            s1[f] = w * cut;
        }
        __syncthreads();
        if (f < 64)
            tabp[j * 64 + f] = (unsigned int)f2h(s1[2 * f]) | ((unsigned int)f2h(s1[2 * f + 1]) << 16);
        return;
    }
    bid -= TN + 1;

    if (bid < 128) {
        // ---- o1w/o2w -> MFMA B-frag-major f16 ----
        int t = bid * 256 + tid;            // 0..32767
        int e = t & 16383;
        int j = e & 7, l = (e >> 3) & 63, nt = (e >> 9) & 7, kt = e >> 12;
        int k = kt * 32 + ((l >> 4) << 3) + j;
        int col = nt * 16 + (l & 15);
        if (t < 16384) o1f[e] = f2h(o1w[k * F + col]);
        else           o2f[e] = f2h(o2w[k * F + col]);
        return;
    }
    bid -= 128;

    {
        // ---- yzp[z] = packed f16 of embed[z] @ in2f; row MAXZ = 0 ----
        int z = bid, f = tid;
        if (z < MAXZ) {
            if (f < F) s0[f] = embed[z * F + f];
            __syncthreads();
            if (f < F) {
                float acc = 0.f;
                #pragma unroll 8
                for (int c = 0; c < F; ++c)
                    acc = fmaf(s0[c], in2f[c * F + f], acc);
                s1[f] = acc;
            }
        } else {
            if (f < F) s1[f] = 0.f;
            __syncthreads();
        }
        __syncthreads();
        if (f < 64)
            yzp[z * 64 + f] = (unsigned int)f2h(s1[2 * f]) | ((unsigned int)f2h(s1[2 * f + 1]) << 16);
    }
}

// ============ fused main: on-the-fly params + pairagg + output net ===========
// 512 threads (8 waves), persistent. Per 16-atom group:
//   pre:    lanes 0-47 build packed params for the wave's 2 atoms (registers)
//   phase1: readlane-broadcast params; f16 lerp+weight+accum (4x12 chunks)
//   phase2: wave w = col-tile w of out-net (MFMA1 -> ssp -> MFMA2 -> +residual)
// LDS: tabL 45312 B | aggL 4096 B | Us 4096 B = 53504 B -> 3 blocks/CU
__global__ __launch_bounds__(512, 6) void k_main(
    const float* __restrict__ dR, const int* __restrict__ nbr,
    const int* __restrict__ Z,
    const unsigned int* __restrict__ tabp,
    const unsigned int* __restrict__ yzp,
    const unsigned short* __restrict__ o1f, const float* __restrict__ o1b,
    const unsigned short* __restrict__ o2f, const float* __restrict__ o2b,
    const float* __restrict__ embed,
    float* __restrict__ out, int N, int ngroups)
{
    extern __shared__ unsigned int smem[];
    unsigned int*   tabL = smem;                                   // 11328 u32
    unsigned int*   aggL = smem + 11328;                           // 1024 u32
    unsigned short* Us   = (unsigned short*)(smem + 11328 + 1024); // 2048 u16

    int tid  = threadIdx.x;
    int wid  = tid >> 6;
    int lane = tid & 63;
    int lr   = lane & 15;
    int lg   = lane >> 4;

    for (int m = tid; m < (TN + 1) * 64; m += 512)
        tabL[m] = tabp[m];
    __syncthreads();

    for (int g = blockIdx.x; g < ngroups; g += gridDim.x) {
        int n0 = g * 16;

        // ---------- phase 1: pair aggregation, 2 atoms per wave ----------
        int aA = wid * 2, aB = aA + 1;
        int nA = n0 + aA, nB = n0 + aB;
        float a0 = 0.f, a1 = 0.f, b0 = 0.f, b1 = 0.f;
        if (nA < N) {
            int mB = (nB < N) ? nB : nA;

            // --- on-the-fly params: lane k holds atom's k-th pair ---
            unsigned int pA = 0, pB = 0;
            if (lane < KN) {
                float dA = dR[nA * KN + lane];
                int   iA = nbr[nA * KN + lane];
                float uA = dA * ((float)TN / 5.0f);
                int   jA = (int)uA; jA = (jA > TN - 1) ? (TN - 1) : jA;
                float fA = uA - (float)jA;
                unsigned int zA = (iA >= 0 && iA < N) ? (unsigned int)Z[iA] : (unsigned int)MAXZ;
                pA = ((unsigned int)f2h(fA) << 16) | ((unsigned int)jA << 7) | zA;

                float dB = dR[mB * KN + lane];
                int   iB = nbr[mB * KN + lane];
                float uB = dB * ((float)TN / 5.0f);
                int   jB = (int)uB; jB = (jB > TN - 1) ? (TN - 1) : jB;
                float fB = uB - (float)jB;
                unsigned int zB = (iB >= 0 && iB < N) ? (unsigned int)Z[iB] : (unsigned int)MAXZ;
                pB = ((unsigned int)f2h(fB) << 16) | ((unsigned int)jB << 7) | zB;
            }

            #pragma unroll
            for (int c = 0; c < 4; ++c) {
                __half2 pacA = u2h2(0u);
                __half2 pacB = u2h2(0u);
                #pragma unroll
                for (int k2 = 0; k2 < 12; ++k2) {
                    int k = c * 12 + k2;
                    unsigned int qA = (unsigned int)__builtin_amdgcn_readlane((int)pA, k);
                    unsigned int qB = (unsigned int)__builtin_amdgcn_readlane((int)pB, k);

                    __half2 frA = u2h2((qA & 0xFFFF0000u) | (qA >> 16));
                    __half2 frB = u2h2((qB & 0xFFFF0000u) | (qB >> 16));
                    unsigned int jbA = (qA & 0x7F80u) << 1;   // j*256 bytes
                    unsigned int jbB = (qB & 0x7F80u) << 1;
                    unsigned int zbA = (qA & 0x7Fu) << 8;     // z*256 bytes
                    unsigned int zbB = (qB & 0x7Fu) << 8;

                    const unsigned int* rA = (const unsigned int*)((const char*)tabL + jbA);
                    const unsigned int* rB = (const unsigned int*)((const char*)tabL + jbB);
                    __half2 tA0 = u2h2(rA[lane]);
                    __half2 tA1 = u2h2(rA[lane + 64]);
                    __half2 tB0 = u2h2(rB[lane]);
                    __half2 tB1 = u2h2(rB[lane + 64]);
                    __half2 yA  = u2h2(*(const unsigned int*)((const char*)yzp + zbA + (lane << 2)));
                    __half2 yB  = u2h2(*(const unsigned int*)((const char*)yzp + zbB + (lane << 2)));

                    __half2 wA = __hfma2(frA, __hsub2(tA1, tA0), tA0);
                    __half2 wB = __hfma2(frB, __hsub2(tB1, tB0), tB0);
                    pacA = __hfma2(wA, yA, pacA);
                    pacB = __hfma2(wB, yB, pacB);
                }
                float2 fa = __half22float2(pacA); a0 += fa.x; a1 += fa.y;
                float2 fb = __half22float2(pacB); b0 += fb.x; b1 += fb.y;
            }
        }
        // swizzled store: word idx = a*64 + (lane ^ (a<<2))
        aggL[aA * 64 + (lane ^ (aA << 2))] = (unsigned int)f2h(a0) | ((unsigned int)f2h(a1) << 16);
        aggL[aB * 64 + (lane ^ (aB << 2))] = (unsigned int)f2h(b0) | ((unsigned int)f2h(b1) << 16);
        __syncthreads();                       // bar1: aggL ready

        // ---------- phase 2: output network (f16 MFMA), col-tile = wid ----------
        f32x4 c1 = {0.f, 0.f, 0.f, 0.f};
        #pragma unroll
        for (int kt = 0; kt < 4; ++kt) {
            f16x8 b = *reinterpret_cast<const f16x8*>(o1f + (((kt * 8 + wid) * 64 + lane) << 3));
            const char* ap = (const char*)aggL + lr * 256 + ((kt * 64 + lg * 16) ^ (lr << 4));
            f16x8 a = *reinterpret_cast<const f16x8*>(ap);
            c1 = __builtin_amdgcn_mfma_f32_16x16x32_f16(a, b, c1, 0, 0, 0);
        }
        int fcol = wid * 16 + lr;
        float bv1 = o1b[fcol];
        #pragma unroll
        for (int jr = 0; jr < 4; ++jr) {
            int r = lg * 4 + jr;
            float u = ssp(c1[jr] + bv1);
            Us[r * F + (fcol ^ (r << 3))] = f2h(u);
        }
        __syncthreads();                       // bar2: Us ready

        f32x4 c2 = {0.f, 0.f, 0.f, 0.f};
        #pragma unroll
        for (int kt = 0; kt < 4; ++kt) {
            f16x8 b = *reinterpret_cast<const f16x8*>(o2f + (((kt * 8 + wid) * 64 + lane) << 3));
            f16x8 a = *reinterpret_cast<const f16x8*>(&Us[lr * F + ((kt * 32 + lg * 8) ^ (lr << 3))]);
            c2 = __builtin_amdgcn_mfma_f32_16x16x32_f16(a, b, c2, 0, 0, 0);
        }
        float bv2 = o2b[fcol];
        #pragma unroll
        for (int jr = 0; jr < 4; ++jr) {
            int r = lg * 4 + jr;
            int n = n0 + r;
            if (n < N) {
                float x = embed[Z[n] * F + fcol];
                out[n * F + fcol] = x + c2[jr] + bv2;
            }
        }
    }
}

extern "C" void kernel_launch(void* const* d_in, const int* in_sizes, int n_in,
                              void* d_out, int out_size, void* d_ws, size_t ws_size,
                              hipStream_t stream) {
    const float* dR    = (const float*)d_in[0];
    const int*   Z     = (const int*)  d_in[1];
    const int*   nbr   = (const int*)  d_in[2];
    const float* embed = (const float*)d_in[3];
    const float* in2f  = (const float*)d_in[4];
    const float* f1w   = (const float*)d_in[5];
    const float* f1b   = (const float*)d_in[6];
    const float* f2w   = (const float*)d_in[7];
    const float* f2b   = (const float*)d_in[8];
    const float* o1w   = (const float*)d_in[9];
    const float* o1b   = (const float*)d_in[10];
    const float* o2w   = (const float*)d_in[11];
    const float* o2b   = (const float*)d_in[12];

    int N = in_sizes[1];

    // ws layout (16B-aligned), ~135 KB total
    char* wp = (char*)d_ws;
    unsigned int*   tabp = (unsigned int*)wp;   wp += (size_t)(TN + 1) * 64 * 4;   // 45.3 KB
    unsigned int*   yzp  = (unsigned int*)wp;   wp += (size_t)(MAXZ + 1) * 64 * 4; // 25.9 KB
    unsigned short* o1f  = (unsigned short*)wp; wp += 16384 * 2;                   // 32 KB
    unsigned short* o2f  = (unsigned short*)wp;                                    // 32 KB

    int grid_prep = (TN + 1) + 128 + (MAXZ + 1);

    int ngroups   = (N + 15) / 16;
    int grid_main = (ngroups < 768) ? ngroups : 768;
    int lds_main  = (TN + 1) * 64 * 4 + 4096 + 4096;   // 53504 B -> 3 blocks/CU

    (void)hipFuncSetAttribute((const void*)k_main,
                              hipFuncAttributeMaxDynamicSharedMemorySize, lds_main);

    k_prep<<<grid_prep, 256, 0, stream>>>(f1w, f1b, f2w, f2b, o1w, o2w,
                                          embed, in2f, tabp, yzp, o1f, o2f, N);
    k_main<<<grid_main, 512, lds_main, stream>>>(dR, nbr, Z, tabp, yzp,
                                                 o1f, o1b, o2f, o2b,
                                                 embed, (float*)d_out,
                                                 N, ngroups);
}